// Round 12
// baseline (1526.644 us; speedup 1.0000x reference)
//
#include <hip/hip_runtime.h>

// RGCN on MI355X — round 19: fused layer stall root-caused.
// r18 ran (WRITE 200->12.5MB as designed) but 694us/layer: NOT bw/compute/
// occupancy bound (148GB/s, MfmaUtil 1.5%, Occ 35%) — stall-bound in the
// aggregation loop. Mechanisms: (1) atomicAdd(float*) on LDS = CAS LOOP
// (ds_read+ds_cmpst+branch per float, lgkm waits serialize the whole loop,
// killing load pipelining) — fix: unsafeAtomicAdd -> native ds_add_f32,
// fire-and-forget; (2) bfr[2][2][4]=64 VGPR double-buffer at VGPR_Count=64
// => B-frags likely in scratch — fix: single-buffer bfr[NTC][4] (32 VGPR),
// issued at TOP of each rel so latency hides under the aggregation phase.
// Pre-commit: fused layer >=250us -> structure condemned -> r20 reverts r16.
// Design (aggregate-then-transform):
//   out[dst] = SUM_r (SUM_{e in(dst),et=r} norm*feat[src]) @ W[r]
// Fast path: to_bf16 -> CSR(et*N+dst) -> fused<128,0> (relu, h) ->
// fused<64,1> -> d_out. Fallback: chunked atomic path (unchanged).

#define R_NUM 16

typedef __attribute__((ext_vector_type(8))) short bf16x8;
typedef __attribute__((ext_vector_type(4))) float f32x4;

__device__ __forceinline__ float bf2f(unsigned short u) {
    unsigned int x = ((unsigned int)u) << 16;
    return __builtin_bit_cast(float, x);
}
__device__ __forceinline__ unsigned short f2bf(float f) {
    unsigned int x = __builtin_bit_cast(unsigned int, f);
    x += 0x7FFFu + ((x >> 16) & 1u);  // RNE
    return (unsigned short)(x >> 16);
}
__device__ __forceinline__ unsigned pack2(float a, float b) {
    return (unsigned)f2bf(a) | ((unsigned)f2bf(b) << 16);
}
__device__ __forceinline__ float lo16(unsigned v) { return bf2f((unsigned short)(v & 0xFFFF)); }
__device__ __forceinline__ float hi16(unsigned v) { return bf2f((unsigned short)(v >> 16)); }

// Raw 16B global load the compiler cannot sink/remat/delete (r12-proven).
__device__ __forceinline__ bf16x8 gload16(const unsigned short* p) {
    bf16x8 r;
    asm volatile("global_load_dwordx4 %0, %1, off" : "=&v"(r) : "v"(p));
    return r;
}

// ---------------- dtype sniffer (fp32 vs bf16 harness inputs) ----------------
__global__ void detect_dtype(const unsigned short* __restrict__ raw, int* flag) {
    __shared__ int tot;
    if (threadIdx.x == 0) tot = 0;
    __syncthreads();
    int c = 0;
    for (int i = threadIdx.x; i < 4096; i += 256) {
        unsigned short u = raw[2 * i];
        int e = (u >> 7) & 0xFF;
        if (e >= 113 && e <= 134) c++;
    }
    atomicAdd(&tot, c);
    __syncthreads();
    if (threadIdx.x == 0) *flag = (tot > 2048) ? 1 : 0;  // 1 => bf16 inputs
}

// Both weight transposes in one launch: W[r][k][o] -> Wt[r][o][k] bf16.
__global__ void transpose_both(const void* __restrict__ W1, const void* __restrict__ W2,
                               unsigned short* __restrict__ w1t, unsigned short* __restrict__ w2t,
                               const int* __restrict__ flagp) {
    const int flag = *flagp;
    const int n1 = R_NUM * 128 * 128;
    const int n2 = R_NUM * 128 * 64;
    int idx = blockIdx.x * 256 + threadIdx.x;
    if (idx < n1) {
        int k = idx % 128, o = (idx / 128) % 128, r = idx / (128 * 128);
        int iin = (r * 128 + k) * 128 + o;
        float v = flag ? bf2f(((const unsigned short*)W1)[iin]) : ((const float*)W1)[iin];
        w1t[idx] = f2bf(v);
    } else if (idx < n1 + n2) {
        int j = idx - n1;
        int k = j % 128, o = (j / 128) % 64, r = j / (128 * 64);
        int iin = (r * 128 + k) * 64 + o;
        float v = flag ? bf2f(((const unsigned short*)W2)[iin]) : ((const float*)W2)[iin];
        w2t[j] = f2bf(v);
    }
}

// Pack node features to bf16 once (n8 = nnodes*16 uint4 segments).
__global__ void to_bf16(const void* __restrict__ in, unsigned short* __restrict__ out, int n8,
                        const int* __restrict__ flagp) {
    int i = blockIdx.x * 256 + threadIdx.x;
    if (i >= n8) return;
    uint4 v;
    if (*flagp) {
        v = ((const uint4*)in)[i];
    } else {
        const float4* p = (const float4*)in + (size_t)i * 2;
        float4 f0 = p[0];
        float4 f1 = p[1];
        v.x = pack2(f0.x, f0.y);
        v.y = pack2(f0.z, f0.w);
        v.z = pack2(f1.x, f1.y);
        v.w = pack2(f1.z, f1.w);
    }
    ((uint4*)out)[i] = v;
}

// ---------------- CSR build over key = et*nnodes + dst ----------------
__global__ void hist_key(const int* __restrict__ dst, const int* __restrict__ et,
                         int* __restrict__ counts, int nedges, int nnodes) {
    int e = blockIdx.x * 256 + threadIdx.x;
    if (e < nedges) atomicAdd(&counts[et[e] * nnodes + dst[e]], 1);
}

__global__ __launch_bounds__(256) void scan_phase1(const int* __restrict__ counts,
                                                   int* __restrict__ blocksums, int n) {
    __shared__ int red[256];
    int base = blockIdx.x * 1024 + threadIdx.x * 4;
    int s = 0;
#pragma unroll
    for (int j = 0; j < 4; j++) {
        int idx = base + j;
        if (idx < n) s += counts[idx];
    }
    red[threadIdx.x] = s;
    __syncthreads();
    for (int d = 128; d > 0; d >>= 1) {
        if (threadIdx.x < d) red[threadIdx.x] += red[threadIdx.x + d];
        __syncthreads();
    }
    if (threadIdx.x == 0) blocksums[blockIdx.x] = red[0];
}

__global__ __launch_bounds__(1024) void scan_phase2(const int* __restrict__ blocksums,
                                                    int* __restrict__ blockoff, int nb) {
    __shared__ int arr[1024];
    int t = threadIdx.x;
    arr[t] = (t < nb) ? blocksums[t] : 0;
    __syncthreads();
    for (int d = 1; d < 1024; d <<= 1) {
        int v = (t >= d) ? arr[t - d] : 0;
        __syncthreads();
        arr[t] += v;
        __syncthreads();
    }
    if (t < nb) blockoff[t] = (t == 0) ? 0 : arr[t - 1];
}

__global__ __launch_bounds__(256) void scan_phase3(const int* __restrict__ counts,
                                                   const int* __restrict__ blockoff,
                                                   int* __restrict__ offsets,
                                                   int* __restrict__ cursor, int n) {
    __shared__ int tsum[256];
    int base = blockIdx.x * 1024 + threadIdx.x * 4;
    int c[4];
    int s = 0;
#pragma unroll
    for (int j = 0; j < 4; j++) {
        int idx = base + j;
        c[j] = (idx < n) ? counts[idx] : 0;
        s += c[j];
    }
    tsum[threadIdx.x] = s;
    __syncthreads();
    for (int d = 1; d < 256; d <<= 1) {
        int v = (threadIdx.x >= d) ? tsum[threadIdx.x - d] : 0;
        __syncthreads();
        tsum[threadIdx.x] += v;
        __syncthreads();
    }
    int run = blockoff[blockIdx.x] + ((threadIdx.x == 0) ? 0 : tsum[threadIdx.x - 1]);
#pragma unroll
    for (int j = 0; j < 4; j++) {
        int idx = base + j;
        if (idx < n) {
            offsets[idx] = run;
            cursor[idx] = run;
            if (idx == n - 1) offsets[n] = run + c[j];
            run += c[j];
        }
    }
}

// payload: pl.x = (dst&31)<<27 | src  (src < 2^27), pl.y = norm fp32
__global__ void fill_payload2(const int* __restrict__ src, const int* __restrict__ dst,
                              const int* __restrict__ et, const void* __restrict__ nrm,
                              const int* __restrict__ flagp, int* __restrict__ cursor,
                              uint2* __restrict__ payload, int nedges, int nnodes) {
    int e = blockIdx.x * 256 + threadIdx.x;
    if (e >= nedges) return;
    int flag = *flagp;
    float nm = flag ? bf2f(((const unsigned short*)nrm)[e]) : ((const float*)nrm)[e];
    int d = dst[e];
    int pos = atomicAdd(&cursor[et[e] * nnodes + d], 1);
    uint2 pl;
    pl.x = ((unsigned)(d & 31) << 27) | (unsigned)src[e];
    pl.y = __builtin_bit_cast(unsigned, nm);
    payload[pos] = pl;
}

// ---------------- fused layer: out[dst] = SUM_r agg_r(dst) @ W[r] ----------
// One block = 32 dst. Per rel: issue B[r] asm loads (latency hides under the
// whole aggregation phase) -> contiguous CSR edge range -> batch-64 payload +
// shfl -> per-edge NATIVE ds_add_f32 (unsafeAtomicAdd, fire-and-forget, no
// CAS loop, loads pipeline freely) into aggF[32][128] -> bf16 convert ->
// vmcnt(0) (B landed) -> MFMA accumulating acc across rels.
// Epilogue: one LDS C-transpose + one contiguous store.
// OUTMODE 0: relu+bf16 (h). OUTMODE 1: flag ? bf16 : fp32 (final output).
template <int NOUT, int OUTMODE>
__global__ __launch_bounds__(256, 3) void fused_layer(const unsigned* __restrict__ featU,
                                                      const unsigned short* __restrict__ Wt,
                                                      const int* __restrict__ offs,
                                                      const uint2* __restrict__ payload,
                                                      void* __restrict__ out, int nnodes,
                                                      const int* __restrict__ flagp) {
    constexpr int NTC = NOUT / 64;
    constexpr int AGF = 132;  // fp32 agg stride (floats)
    constexpr int ABS = 136;  // bf16 agg stride (shorts)
    __shared__ float aggF[32 * AGF];           // 16.9 KB
    __shared__ unsigned short aggB[32 * ABS];  // 8.7 KB
    const int tid = threadIdx.x;
    const int node0 = blockIdx.x * 32;
    const int w = tid >> 6, lane = tid & 63;
    const int quad = lane >> 4, mr = lane & 15;

    // wave-private B rows of Wt[r]: row w*16+mr (+c*64), 16B chunk per quad
    const unsigned short* wbase = Wt + ((size_t)(w * 16 + mr)) * 128 + quad * 8;
    bf16x8 bfr[NTC][4];  // single-buffered: 32 VGPR (r18's 64-reg dbuf spilled)

    for (int i = tid; i < 32 * AGF; i += 256) aggF[i] = 0.f;

    f32x4 acc[2][NTC];
#pragma unroll
    for (int mt = 0; mt < 2; mt++)
#pragma unroll
        for (int c = 0; c < NTC; c++) acc[mt][c] = 0.f;

    __syncthreads();

    for (int r = 0; r < R_NUM; r++) {
        // issue B[r] now; its ~600cy latency hides under the aggregation
#pragma unroll
        for (int c = 0; c < NTC; c++)
#pragma unroll
            for (int kk = 0; kk < 4; kk++)
                bfr[c][kk] = gload16(wbase + (size_t)(r * NOUT + c * 64) * 128 + kk * 32);

        // ---- aggregation: edges of (rel r, dst in [node0, node0+32)) ----
        const int kb = r * nnodes + node0;
        const int ke = r * nnodes + min(node0 + 32, nnodes);
        const int beg = offs[kb], end = offs[ke];
        const int m = end - beg;
        const int per = (m + 3) >> 2;
        const int cb = min(beg + w * per, end);
        const int ce = min(cb + per, end);
        for (int i = cb; i < ce; i += 64) {
            int cnt = min(64, ce - i);
            uint2 pl = make_uint2(0u, 0u);
            if (lane < cnt) pl = payload[i + lane];
            int j = 0;
            for (; j + 4 <= cnt; j += 4) {
                unsigned x0 = (unsigned)__shfl((int)pl.x, j);
                unsigned x1 = (unsigned)__shfl((int)pl.x, j + 1);
                unsigned x2 = (unsigned)__shfl((int)pl.x, j + 2);
                unsigned x3 = (unsigned)__shfl((int)pl.x, j + 3);
                float n0 = __builtin_bit_cast(float, (unsigned)__shfl((int)pl.y, j));
                float n1 = __builtin_bit_cast(float, (unsigned)__shfl((int)pl.y, j + 1));
                float n2 = __builtin_bit_cast(float, (unsigned)__shfl((int)pl.y, j + 2));
                float n3 = __builtin_bit_cast(float, (unsigned)__shfl((int)pl.y, j + 3));
                unsigned v0 = featU[(size_t)(x0 & 0x07FFFFFFu) * 64 + lane];
                unsigned v1 = featU[(size_t)(x1 & 0x07FFFFFFu) * 64 + lane];
                unsigned v2 = featU[(size_t)(x2 & 0x07FFFFFFu) * 64 + lane];
                unsigned v3 = featU[(size_t)(x3 & 0x07FFFFFFu) * 64 + lane];
                float* p0 = aggF + (x0 >> 27) * AGF + 2 * lane;
                float* p1 = aggF + (x1 >> 27) * AGF + 2 * lane;
                float* p2 = aggF + (x2 >> 27) * AGF + 2 * lane;
                float* p3 = aggF + (x3 >> 27) * AGF + 2 * lane;
                unsafeAtomicAdd(p0, lo16(v0) * n0);
                unsafeAtomicAdd(p0 + 1, hi16(v0) * n0);
                unsafeAtomicAdd(p1, lo16(v1) * n1);
                unsafeAtomicAdd(p1 + 1, hi16(v1) * n1);
                unsafeAtomicAdd(p2, lo16(v2) * n2);
                unsafeAtomicAdd(p2 + 1, hi16(v2) * n2);
                unsafeAtomicAdd(p3, lo16(v3) * n3);
                unsafeAtomicAdd(p3 + 1, hi16(v3) * n3);
            }
            for (; j < cnt; j++) {
                unsigned x = (unsigned)__shfl((int)pl.x, j);
                float nm = __builtin_bit_cast(float, (unsigned)__shfl((int)pl.y, j));
                unsigned v = featU[(size_t)(x & 0x07FFFFFFu) * 64 + lane];
                float* p = aggF + (x >> 27) * AGF + 2 * lane;
                unsafeAtomicAdd(p, lo16(v) * nm);
                unsafeAtomicAdd(p + 1, hi16(v) * nm);
            }
        }
        __syncthreads();  // agg visible block-wide (ds_adds drained by lgkmcnt)

        // ---- convert fp32 -> bf16 (and zero aggF for next rel) ----
        for (int i = tid; i < 32 * 32; i += 256) {  // 32 rows x 32 float4
            int row = i >> 5, c4 = i & 31;
            float4 f = *(float4*)(aggF + row * AGF + c4 * 4);
            *(float4*)(aggF + row * AGF + c4 * 4) = make_float4(0.f, 0.f, 0.f, 0.f);
            uint2 pv;
            pv.x = pack2(f.x, f.y);
            pv.y = pack2(f.z, f.w);
            *(uint2*)(aggB + row * ABS + c4 * 4) = pv;
        }
        __syncthreads();  // aggB ready, aggF zeroed

        // rule 18: bfr from asm loads — force the wait + scheduling fence so
        // no MFMA precedes B[r] landing (it landed long ago, under the agg).
        asm volatile("s_waitcnt vmcnt(0)" ::: "memory");
        __builtin_amdgcn_sched_barrier(0);

        // ---- MFMA: acc += (aggB @ W[r])^T fragments ----
#pragma unroll
        for (int kk = 0; kk < 4; kk++) {
            bf16x8 a[2];
#pragma unroll
            for (int mt = 0; mt < 2; mt++)
                a[mt] = *(const bf16x8*)(aggB + (mt * 16 + mr) * ABS + kk * 32 + quad * 8);
#pragma unroll
            for (int c = 0; c < NTC; c++)
#pragma unroll
                for (int mt = 0; mt < 2; mt++)
                    acc[mt][c] = __builtin_amdgcn_mfma_f32_16x16x32_bf16(bfr[c][kk], a[mt],
                                                                         acc[mt][c], 0, 0, 0);
        }
        __syncthreads();  // aggB reads done before next convert overwrites
    }

    // ---- epilogue: acc -> LDS transpose -> one contiguous store ----
    const int flag = (OUTMODE == 1) ? *flagp : 0;
    if (OUTMODE == 0 || flag) {
        constexpr int LDC = NOUT + 8;
#pragma unroll
        for (int mt = 0; mt < 2; mt++)
#pragma unroll
            for (int c = 0; c < NTC; c++) {
                float x0 = acc[mt][c][0], x1 = acc[mt][c][1];
                float x2 = acc[mt][c][2], x3 = acc[mt][c][3];
                if (OUTMODE == 0) {
                    x0 = fmaxf(x0, 0.f);
                    x1 = fmaxf(x1, 0.f);
                    x2 = fmaxf(x2, 0.f);
                    x3 = fmaxf(x3, 0.f);
                }
                uint2 pv;
                pv.x = pack2(x0, x1);
                pv.y = pack2(x2, x3);
                *(uint2*)(aggB + (mt * 16 + mr) * LDC + c * 64 + w * 16 + quad * 4) = pv;
            }
        __syncthreads();
        constexpr int SEGS = NOUT / 8;
        for (int i = tid; i < 32 * SEGS; i += 256) {
            int row = i / SEGS, seg = i % SEGS;
            int node = node0 + row;
            if (node < nnodes)
                *(uint4*)((unsigned short*)out + (size_t)node * NOUT + seg * 8) =
                    *(const uint4*)(aggB + row * LDC + seg * 8);
        }
    } else {
        constexpr int LDCF = NOUT + 4;
#pragma unroll
        for (int mt = 0; mt < 2; mt++)
#pragma unroll
            for (int c = 0; c < NTC; c++) {
                *(float4*)(aggF + (mt * 16 + mr) * LDCF + c * 64 + w * 16 + quad * 4) =
                    make_float4(acc[mt][c][0], acc[mt][c][1], acc[mt][c][2], acc[mt][c][3]);
            }
        __syncthreads();
        constexpr int SEGF = NOUT / 4;
        for (int i = tid; i < 32 * SEGF; i += 256) {
            int row = i / SEGF, seg = i % SEGF;
            int node = node0 + row;
            if (node < nnodes)
                *(float4*)((float*)out + (size_t)node * NOUT + seg * 4) =
                    *(const float4*)(aggF + row * LDCF + seg * 4);
        }
    }
}

// ---------------- fallback path (chunked + atomics, node-major t) ----------------
template <int NOUT, int AMODE>
__global__ __launch_bounds__(256) void gemm_rel(const void* __restrict__ Asrc,
                                                const unsigned short* __restrict__ Wt,
                                                unsigned short* __restrict__ T, int nnodes,
                                                int rbase, const int* __restrict__ flagp) {
    constexpr int LDA = 136;
    __shared__ unsigned short lA[64 * LDA];
    __shared__ unsigned short lB[NOUT * LDA];
    const int tid = threadIdx.x;
    const int node0 = blockIdx.x * 64;
    const int rel = rbase + blockIdx.y;
    const int Gr = gridDim.y;
    const int flag = (AMODE == 0) ? *flagp : 1;

    for (int i = tid; i < 64 * 16; i += 256) {
        int row = i >> 4, seg = i & 15;
        int node = node0 + row;
        uint4 v = make_uint4(0u, 0u, 0u, 0u);
        if (node < nnodes) {
            if (AMODE == 1) {
                const float* p = (const float*)Asrc + (size_t)node * 128 + seg * 8;
                float4 f0 = ((const float4*)p)[0];
                float4 f1 = ((const float4*)p)[1];
                v.x = pack2(fmaxf(f0.x, 0.f), fmaxf(f0.y, 0.f));
                v.y = pack2(fmaxf(f0.z, 0.f), fmaxf(f0.w, 0.f));
                v.z = pack2(fmaxf(f1.x, 0.f), fmaxf(f1.y, 0.f));
                v.w = pack2(fmaxf(f1.z, 0.f), fmaxf(f1.w, 0.f));
            } else if (flag) {
                v = *(const uint4*)((const unsigned short*)Asrc + (size_t)node * 128 + seg * 8);
            } else {
                const float* p = (const float*)Asrc + (size_t)node * 128 + seg * 8;
                float4 f0 = ((const float4*)p)[0];
                float4 f1 = ((const float4*)p)[1];
                v.x = pack2(f0.x, f0.y);
                v.y = pack2(f0.z, f0.w);
                v.z = pack2(f1.x, f1.y);
                v.w = pack2(f1.z, f1.w);
            }
        }
        *(uint4*)(lA + row * LDA + seg * 8) = v;
    }
    for (int i = tid; i < NOUT * 16; i += 256) {
        int o = i >> 4, seg = i & 15;
        *(uint4*)(lB + o * LDA + seg * 8) =
            *(const uint4*)(Wt + ((size_t)rel * NOUT + o) * 128 + seg * 8);
    }
    __syncthreads();

    const int w = tid >> 6, lane = tid & 63;
    const int quad = lane >> 4, mr = lane & 15;
    constexpr int NT = NOUT / 16;
    f32x4 acc[NT];
#pragma unroll
    for (int t = 0; t < NT; t++) acc[t] = 0.f;
    const unsigned short* pa = lA + (w * 16 + mr) * LDA + quad * 8;
    const unsigned short* pb = lB + mr * LDA + quad * 8;
#pragma unroll
    for (int kk = 0; kk < 4; kk++) {
        bf16x8 a = *(const bf16x8*)(pa + kk * 32);
#pragma unroll
        for (int nt = 0; nt < NT; nt++) {
            bf16x8 b = *(const bf16x8*)(pb + nt * 16 * LDA + kk * 32);
            acc[nt] = __builtin_amdgcn_mfma_f32_16x16x32_bf16(a, b, acc[nt], 0, 0, 0);
        }
    }
#pragma unroll
    for (int nt = 0; nt < NT; nt++)
#pragma unroll
        for (int reg = 0; reg < 4; reg++) {
            int node = node0 + w * 16 + quad * 4 + reg;
            if (node < nnodes)
                T[((size_t)node * Gr + blockIdx.y) * NOUT + nt * 16 + mr] = f2bf(acc[nt][reg]);
        }
}

template <int NOUT>
__global__ void scatter_k(const unsigned short* __restrict__ T, int Gr, int rbase,
                          const void* __restrict__ nrm, const int* __restrict__ flagp,
                          const int* __restrict__ src, const int* __restrict__ dst,
                          const int* __restrict__ et, float* __restrict__ accum, int nedges) {
    constexpr int LPE = NOUT / 2;
    const int flag = *flagp;
    const int epb = 256 / LPE;
    const int sub = threadIdx.x % LPE;
    const int slot = threadIdx.x / LPE;
    for (int e = blockIdx.x * epb + slot; e < nedges; e += gridDim.x * epb) {
        int g = et[e] - rbase;
        if (g < 0 || g >= Gr) continue;
        int s = src[e], d = dst[e];
        float nm = flag ? bf2f(((const unsigned short*)nrm)[e]) : ((const float*)nrm)[e];
        unsigned pv = ((const unsigned*)(T + ((size_t)s * Gr + g) * NOUT))[sub];
        float* p = accum + (size_t)d * NOUT + sub * 2;
        unsafeAtomicAdd(p, lo16(pv) * nm);
        unsafeAtomicAdd(p + 1, hi16(pv) * nm);
    }
}

__global__ void write_out(const float* __restrict__ acc, void* __restrict__ dout, int n,
                          const int* __restrict__ flagp) {
    int flag = *flagp;
    int i = blockIdx.x * 256 + threadIdx.x;
    if (i >= n) return;
    float v = acc[i];
    if (flag) ((unsigned short*)dout)[i] = f2bf(v);
    else      ((float*)dout)[i] = v;
}

extern "C" void kernel_launch(void* const* d_in, const int* in_sizes, int n_in,
                              void* d_out, int out_size, void* d_ws, size_t ws_size,
                              hipStream_t stream) {
    const void* feat = d_in[0];
    const void* norm = d_in[1];
    const void* W1 = d_in[2];
    const void* W2 = d_in[3];
    const int* src = (const int*)d_in[4];
    const int* dst = (const int*)d_in[5];
    const int* et  = (const int*)d_in[6];

    const int nnodes = in_sizes[0] / 128;
    const int nedges = in_sizes[1];

    char* ws = (char*)d_ws;
    size_t off = 0;
    auto alloc = [&](size_t bytes) { size_t o = off; off += (bytes + 255) & ~255ULL; return o; };
    size_t off_flag = alloc(4);
    size_t off_w1t  = alloc((size_t)R_NUM * 128 * 128 * 2);
    size_t off_w2t  = alloc((size_t)R_NUM * 64 * 128 * 2);

    int* flagp = (int*)(ws + off_flag);
    unsigned short* w1t = (unsigned short*)(ws + off_w1t);
    unsigned short* w2t = (unsigned short*)(ws + off_w2t);

    const size_t nkeys = (size_t)R_NUM * nnodes;

    // fast-path layout
    size_t f_off = off;
    auto falloc = [&](size_t bytes) { size_t o = f_off; f_off += (bytes + 255) & ~255ULL; return o; };
    size_t off_offs = falloc((nkeys + 1) * 4);
    size_t off_curs = falloc(nkeys * 4);
    size_t off_cnt  = falloc(nkeys * 4);
    size_t off_bsum = falloc(1024 * 4);
    size_t off_boff = falloc(1024 * 4);
    size_t off_pay  = falloc((size_t)nedges * 8);
    size_t off_nbf  = falloc((size_t)nnodes * 128 * 2);  // feat bf16
    size_t off_hbf  = falloc((size_t)nnodes * 128 * 2);  // h bf16
    const int nb = (int)((nkeys + 1023) / 1024);
    bool fast = (f_off <= ws_size) && (nb <= 1024) && (nnodes <= 65536);

    const int ntr = R_NUM * 128 * 128 + R_NUM * 128 * 64;

    detect_dtype<<<1, 256, 0, stream>>>((const unsigned short*)feat, flagp);
    transpose_both<<<(ntr + 255) / 256, 256, 0, stream>>>(W1, W2, w1t, w2t, flagp);

    if (fast) {
        int* offs = (int*)(ws + off_offs);
        int* curs = (int*)(ws + off_curs);
        int* cnt  = (int*)(ws + off_cnt);
        int* bsum = (int*)(ws + off_bsum);
        int* boff = (int*)(ws + off_boff);
        uint2* pay = (uint2*)(ws + off_pay);
        unsigned short* nbf = (unsigned short*)(ws + off_nbf);
        unsigned short* hbf = (unsigned short*)(ws + off_hbf);

        hipMemsetAsync(cnt, 0, nkeys * 4, stream);
        hist_key<<<(nedges + 255) / 256, 256, 0, stream>>>(dst, et, cnt, nedges, nnodes);
        scan_phase1<<<nb, 256, 0, stream>>>(cnt, bsum, (int)nkeys);
        scan_phase2<<<1, 1024, 0, stream>>>(bsum, boff, nb);
        scan_phase3<<<nb, 256, 0, stream>>>(cnt, boff, offs, curs, (int)nkeys);
        fill_payload2<<<(nedges + 255) / 256, 256, 0, stream>>>(src, dst, et, norm, flagp,
                                                                curs, pay, nedges, nnodes);

        const int n8 = nnodes * 16;
        to_bf16<<<(n8 + 255) / 256, 256, 0, stream>>>(feat, nbf, n8, flagp);

        const int gxf = (nnodes + 31) / 32;
        fused_layer<128, 0><<<gxf, 256, 0, stream>>>((const unsigned*)nbf, w1t, offs, pay, hbf,
                                                     nnodes, flagp);
        fused_layer<64, 1><<<gxf, 256, 0, stream>>>((const unsigned*)hbf, w2t, offs, pay, d_out,
                                                    nnodes, flagp);
        return;
    }

    // fallback: chunked atomic path
    size_t off_hpre = alloc((size_t)nnodes * 128 * 4);
    size_t off_oacc = alloc((size_t)nnodes * 64 * 4);
    size_t t_cap = (ws_size > off) ? (ws_size - off) : 0;
    auto pick_gr = [&](int ncol) {
        int gr = 0;
        for (int g = 16; g >= 1; g >>= 1)
            if ((size_t)nnodes * g * ncol * 2 <= t_cap) { gr = g; break; }
        return gr;
    };
    int Gr1 = pick_gr(128);
    int Gr2 = pick_gr(64);
    if (Gr1 < 1 || Gr2 < 1) {
        hipMemsetAsync(d_out, 0x42, (size_t)out_size * 2, stream);
        return;
    }
    float* hpre = (float*)(ws + off_hpre);
    float* oacc = (float*)(ws + off_oacc);
    unsigned short* t = (unsigned short*)(ws + off);
    const int gx = (nnodes + 63) / 64;

    hipMemsetAsync(hpre, 0, (size_t)nnodes * 128 * 4, stream);
    hipMemsetAsync(oacc, 0, (size_t)nnodes * 64 * 4, stream);
    for (int rb = 0; rb < R_NUM; rb += Gr1) {
        gemm_rel<128, 0><<<dim3(gx, Gr1), 256, 0, stream>>>(feat, w1t, t, nnodes, rb, flagp);
        scatter_k<128><<<4096, 256, 0, stream>>>(t, Gr1, rb, norm, flagp, src, dst, et, hpre, nedges);
    }
    for (int rb = 0; rb < R_NUM; rb += Gr2) {
        gemm_rel<64, 1><<<dim3(gx, Gr2), 256, 0, stream>>>(hpre, w2t, t, nnodes, rb, flagp);
        scatter_k<64><<<4096, 256, 0, stream>>>(t, Gr2, rb, norm, flagp, src, dst, et, oacc, nedges);
    }
    int nout = nnodes * 64;
    write_out<<<(nout + 255) / 256, 256, 0, stream>>>(oacc, d_out, nout, flagp);
}

// Round 13
// 360.772 us; speedup vs baseline: 4.2316x; 4.2316x over previous
//
#include <hip/hip_runtime.h>

// RGCN on MI355X — round 20: REVERT to r16 (best verified: 360.0us).
// The fused aggregate-then-transform arc (r17-r19) is condemned per the r19
// pre-commitment: fused layers pinned at ~700us across two structurally
// different variants (CAS vs native LDS atomic, 64 vs 48 VGPR) with nothing
// saturated (HBM 1.8%, Mfma 1.5%, VALU 4.8%, Occ 40%) — the 48-barrier-phase
// per-block structure with ~8 edges/wave/phase is latency-pathological and
// the precise mechanism is not identifiable from counters. r16 is the best
// harness-verified kernel: materialized-T, RPB=4 rel-loop with counted vmcnt
// (wave-uniform unconditional npad stores), raw lgkm-only barriers for the
// LDS C-transpose, asm double-buffered B in regs, stores never drained.
// Measured (round 9): gemm1 80us, total 360.0us, absmax 0.0625.
// Fast path:
//   to_bf16: feat -> nbf; CSR(dst); t1 = nbf@W1 (gemm_plane<128,4>, gx*4);
//   gather1 -> relu -> nbf; t2 = nbf@W2 (gemm_plane<64,4>); gather2 -> d_out.
// Fallback (small ws): chunked atomic path (unchanged).

#define R_NUM 16

typedef __attribute__((ext_vector_type(8))) short bf16x8;
typedef __attribute__((ext_vector_type(4))) float f32x4;

__device__ __forceinline__ float bf2f(unsigned short u) {
    unsigned int x = ((unsigned int)u) << 16;
    return __builtin_bit_cast(float, x);
}
__device__ __forceinline__ unsigned short f2bf(float f) {
    unsigned int x = __builtin_bit_cast(unsigned int, f);
    x += 0x7FFFu + ((x >> 16) & 1u);  // RNE
    return (unsigned short)(x >> 16);
}
__device__ __forceinline__ unsigned pack2(float a, float b) {
    return (unsigned)f2bf(a) | ((unsigned)f2bf(b) << 16);
}
__device__ __forceinline__ float lo16(unsigned v) { return bf2f((unsigned short)(v & 0xFFFF)); }
__device__ __forceinline__ float hi16(unsigned v) { return bf2f((unsigned short)(v >> 16)); }

// Raw 16B global load the compiler cannot sink/remat/delete (r12-proven).
__device__ __forceinline__ bf16x8 gload16(const unsigned short* p) {
    bf16x8 r;
    asm volatile("global_load_dwordx4 %0, %1, off" : "=&v"(r) : "v"(p));
    return r;
}

// ---------------- dtype sniffer (fp32 vs bf16 harness inputs) ----------------
__global__ void detect_dtype(const unsigned short* __restrict__ raw, int* flag) {
    __shared__ int tot;
    if (threadIdx.x == 0) tot = 0;
    __syncthreads();
    int c = 0;
    for (int i = threadIdx.x; i < 4096; i += 256) {
        unsigned short u = raw[2 * i];
        int e = (u >> 7) & 0xFF;
        if (e >= 113 && e <= 134) c++;
    }
    atomicAdd(&tot, c);
    __syncthreads();
    if (threadIdx.x == 0) *flag = (tot > 2048) ? 1 : 0;  // 1 => bf16 inputs
}

// Both weight transposes in one launch: W[r][k][o] -> Wt[r][o][k] bf16.
__global__ void transpose_both(const void* __restrict__ W1, const void* __restrict__ W2,
                               unsigned short* __restrict__ w1t, unsigned short* __restrict__ w2t,
                               const int* __restrict__ flagp) {
    const int flag = *flagp;
    const int n1 = R_NUM * 128 * 128;
    const int n2 = R_NUM * 128 * 64;
    int idx = blockIdx.x * 256 + threadIdx.x;
    if (idx < n1) {
        int k = idx % 128, o = (idx / 128) % 128, r = idx / (128 * 128);
        int iin = (r * 128 + k) * 128 + o;
        float v = flag ? bf2f(((const unsigned short*)W1)[iin]) : ((const float*)W1)[iin];
        w1t[idx] = f2bf(v);
    } else if (idx < n1 + n2) {
        int j = idx - n1;
        int k = j % 128, o = (j / 128) % 64, r = j / (128 * 64);
        int iin = (r * 128 + k) * 64 + o;
        float v = flag ? bf2f(((const unsigned short*)W2)[iin]) : ((const float*)W2)[iin];
        w2t[j] = f2bf(v);
    }
}

// Pack node features to bf16 once (n8 = nnodes*16 uint4 segments).
__global__ void to_bf16(const void* __restrict__ in, unsigned short* __restrict__ out, int n8,
                        const int* __restrict__ flagp) {
    int i = blockIdx.x * 256 + threadIdx.x;
    if (i >= n8) return;
    uint4 v;
    if (*flagp) {
        v = ((const uint4*)in)[i];
    } else {
        const float4* p = (const float4*)in + (size_t)i * 2;
        float4 f0 = p[0];
        float4 f1 = p[1];
        v.x = pack2(f0.x, f0.y);
        v.y = pack2(f0.z, f0.w);
        v.z = pack2(f1.x, f1.y);
        v.w = pack2(f1.z, f1.w);
    }
    ((uint4*)out)[i] = v;
}

// ---------------- GEMM: one (64-node tile, RPB rels) per block -------------
// Transposed MFMA: acc = mfma(Wfrag, featfrag) = (feat@W)^T fragments: lane
// (quad,mr) owns node mt*16+mr, cols c*64+w*16+quad*4..+3.
// Per rel: counted vmcnt retires prefetched asm B-loads (leaves prev rel's
// stores in flight) -> MFMA (lA ds_reads + reg B) -> issue B[r+1] -> pack ->
// ds_write lC -> raw barrier(lgkm only) -> contiguous UNCONDITIONAL store
// (fire&forget, wave-uniform count) -> raw barrier(lgkm only).
// T is npad-strided: padding rows land in padding, never on real data.
template <int NOUT, int RPB>
__global__ __launch_bounds__(256, 3) void gemm_plane(const unsigned short* __restrict__ A,
                                                     const unsigned short* __restrict__ Wt,
                                                     unsigned short* __restrict__ T, int nnodes,
                                                     int npad) {
    constexpr int LDA = 136;
    constexpr int LDC = NOUT + 8;
    constexpr int NTC = NOUT / 64;
    constexpr int SEGS = NOUT / 8;
    constexpr int SPT = 64 * SEGS / 256;  // global stores per thread per rel
    constexpr int NGRP = R_NUM / RPB;
    __shared__ unsigned short lA[64 * LDA];  // A-tile, persists all RPB rels
    __shared__ unsigned short lC[64 * LDC];  // C transpose staging
    const int tid = threadIdx.x;
    const int rbase = (blockIdx.x % NGRP) * RPB;  // rel-group fastest
    const int node0 = (blockIdx.x / NGRP) * 64;
    const int w = tid >> 6, lane = tid & 63;
    const int quad = lane >> 4, mr = lane & 15;

    // wave-private B row base: row (w*16+mr) of Wt[rel], 16B chunk per quad
    const unsigned short* wbase = Wt + ((size_t)(w * 16 + mr)) * 128 + quad * 8;

    bf16x8 bfr[2][NTC][4];  // double-buffered B frags (static index per unrolled copy)
#pragma unroll
    for (int c = 0; c < NTC; c++)
#pragma unroll
        for (int kk = 0; kk < 4; kk++)
            bfr[0][c][kk] = gload16(wbase + (size_t)(rbase * NOUT + c * 64) * 128 + kk * 32);

    // stage A once: 64 rows x 16 segs of 8 bf16 (uint4), coalesced
    for (int i = tid; i < 64 * 16; i += 256) {
        int row = i >> 4, seg = i & 15;
        int node = node0 + row;
        uint4 v = make_uint4(0u, 0u, 0u, 0u);
        if (node < nnodes) v = *(const uint4*)(A + (size_t)node * 128 + seg * 8);
        *(uint4*)(lA + row * LDA + seg * 8) = v;
    }
    __syncthreads();  // full drain once: A staged
    // rule 18: bfr[0] comes from asm loads the compiler can't track — force
    // the wait + a scheduling fence so no MFMA precedes B[0] landing.
    asm volatile("s_waitcnt vmcnt(0)" ::: "memory");
    __builtin_amdgcn_sched_barrier(0);

#pragma unroll
    for (int rr = 0; rr < RPB; rr++) {
        const int r = rbase + rr;
        // retire B[r] (prefetched last rel); leave prev rel's SPT stores in
        // flight. Counting is exact: EVERY wave issues exactly NTC*4 loads +
        // SPT stores per rel (stores unconditional).
        if (rr > 0) {
            if constexpr (NOUT == 128)
                asm volatile("s_waitcnt vmcnt(4)" ::: "memory");
            else
                asm volatile("s_waitcnt vmcnt(2)" ::: "memory");
            __builtin_amdgcn_sched_barrier(0);
        }

        f32x4 acc[4][NTC];
#pragma unroll
        for (int mt = 0; mt < 4; mt++)
#pragma unroll
            for (int c = 0; c < NTC; c++) acc[mt][c] = 0.f;

#pragma unroll
        for (int kk = 0; kk < 4; kk++) {
            bf16x8 a[4];
#pragma unroll
            for (int mt = 0; mt < 4; mt++)
                a[mt] = *(const bf16x8*)(lA + (mt * 16 + mr) * LDA + kk * 32 + quad * 8);
#pragma unroll
            for (int c = 0; c < NTC; c++)
#pragma unroll
                for (int mt = 0; mt < 4; mt++)
                    acc[mt][c] = __builtin_amdgcn_mfma_f32_16x16x32_bf16(bfr[rr & 1][c][kk], a[mt],
                                                                         acc[mt][c], 0, 0, 0);
        }

        // prefetch B[r+1] (latency hides under pack/stage/store below)
        if (rr + 1 < RPB) {
#pragma unroll
            for (int c = 0; c < NTC; c++)
#pragma unroll
                for (int kk = 0; kk < 4; kk++)
                    bfr[(rr + 1) & 1][c][kk] =
                        gload16(wbase + (size_t)((r + 1) * NOUT + c * 64) * 128 + kk * 32);
        }

        // pack acc -> lC (the transpose), b64 per (mt,c)
#pragma unroll
        for (int mt = 0; mt < 4; mt++)
#pragma unroll
            for (int c = 0; c < NTC; c++) {
                uint2 pv;
                pv.x = pack2(acc[mt][c][0], acc[mt][c][1]);
                pv.y = pack2(acc[mt][c][2], acc[mt][c][3]);
                *(uint2*)(lC + (mt * 16 + mr) * LDC + c * 64 + w * 16 + quad * 4) = pv;
            }

        // raw barrier: lgkm only — stores stay in flight
        asm volatile("s_waitcnt lgkmcnt(0)" ::: "memory");
        __builtin_amdgcn_sched_barrier(0);
        __builtin_amdgcn_s_barrier();
        __builtin_amdgcn_sched_barrier(0);

        // contiguous fire-and-forget store: 64*NOUT*2 B at T[r][node0], npad
        // stride, UNCONDITIONAL (padding rows are zeros, land in padding).
#pragma unroll
        for (int it = 0; it < SPT; it++) {
            int i = it * 256 + tid;
            int row = i / SEGS, seg = i % SEGS;
            *(uint4*)(T + ((size_t)r * npad + node0 + row) * NOUT + seg * 8) =
                *(const uint4*)(lC + row * LDC + seg * 8);
        }

        // raw barrier: lC reads retired (lgkm) before next rel overwrites
        asm volatile("s_waitcnt lgkmcnt(0)" ::: "memory");
        __builtin_amdgcn_sched_barrier(0);
        __builtin_amdgcn_s_barrier();
        __builtin_amdgcn_sched_barrier(0);
    }
}

// ---------------- CSR build ----------------
__global__ void hist_dst(const int* __restrict__ dst, int* __restrict__ counts, int nedges) {
    int e = blockIdx.x * 256 + threadIdx.x;
    if (e < nedges) atomicAdd(&counts[dst[e]], 1);
}

__global__ __launch_bounds__(256) void scan_phase1(const int* __restrict__ counts,
                                                   int* __restrict__ blocksums, int n) {
    __shared__ int red[256];
    int base = blockIdx.x * 1024 + threadIdx.x * 4;
    int s = 0;
#pragma unroll
    for (int j = 0; j < 4; j++) {
        int idx = base + j;
        if (idx < n) s += counts[idx];
    }
    red[threadIdx.x] = s;
    __syncthreads();
    for (int d = 128; d > 0; d >>= 1) {
        if (threadIdx.x < d) red[threadIdx.x] += red[threadIdx.x + d];
        __syncthreads();
    }
    if (threadIdx.x == 0) blocksums[blockIdx.x] = red[0];
}

__global__ __launch_bounds__(1024) void scan_phase2(const int* __restrict__ blocksums,
                                                    int* __restrict__ blockoff, int nb) {
    __shared__ int arr[1024];
    int t = threadIdx.x;
    arr[t] = (t < nb) ? blocksums[t] : 0;
    __syncthreads();
    for (int d = 1; d < 1024; d <<= 1) {
        int v = (t >= d) ? arr[t - d] : 0;
        __syncthreads();
        arr[t] += v;
        __syncthreads();
    }
    if (t < nb) blockoff[t] = (t == 0) ? 0 : arr[t - 1];
}

__global__ __launch_bounds__(256) void scan_phase3(const int* __restrict__ counts,
                                                   const int* __restrict__ blockoff,
                                                   int* __restrict__ offsets,
                                                   int* __restrict__ cursor, int n) {
    __shared__ int tsum[256];
    int base = blockIdx.x * 1024 + threadIdx.x * 4;
    int c[4];
    int s = 0;
#pragma unroll
    for (int j = 0; j < 4; j++) {
        int idx = base + j;
        c[j] = (idx < n) ? counts[idx] : 0;
        s += c[j];
    }
    tsum[threadIdx.x] = s;
    __syncthreads();
    for (int d = 1; d < 256; d <<= 1) {
        int v = (threadIdx.x >= d) ? tsum[threadIdx.x - d] : 0;
        __syncthreads();
        tsum[threadIdx.x] += v;
        __syncthreads();
    }
    int run = blockoff[blockIdx.x] + ((threadIdx.x == 0) ? 0 : tsum[threadIdx.x - 1]);
#pragma unroll
    for (int j = 0; j < 4; j++) {
        int idx = base + j;
        if (idx < n) {
            offsets[idx] = run;
            cursor[idx] = run;
            if (idx == n - 1) offsets[n] = run + c[j];
            run += c[j];
        }
    }
}

__global__ void fill_payload(const int* __restrict__ src, const int* __restrict__ dst,
                             const int* __restrict__ et, const void* __restrict__ nrm,
                             const int* __restrict__ flagp, int* __restrict__ cursor,
                             uint2* __restrict__ payload, int nedges) {
    int e = blockIdx.x * 256 + threadIdx.x;
    if (e >= nedges) return;
    int flag = *flagp;
    float nm = flag ? bf2f(((const unsigned short*)nrm)[e]) : ((const float*)nrm)[e];
    int pos = atomicAdd(&cursor[dst[e]], 1);
    uint2 pl;
    pl.x = ((unsigned)src[e] << 4) | (unsigned)(et[e] & 15);
    pl.y = __builtin_bit_cast(unsigned, nm);
    payload[pos] = pl;
}

// ---------------- dst-centric gather (atomic-free) ----------------
// T is rel-major, npad-strided: row = T[(et*npad + src)*NOUT].
template <int NOUT, int OUTMODE>
__global__ __launch_bounds__(256) void gather_seg(const unsigned short* __restrict__ T,
                                                  const int* __restrict__ offsets,
                                                  const uint2* __restrict__ payload,
                                                  void* __restrict__ out, int nnodes, int npad,
                                                  const int* __restrict__ flagp) {
    constexpr int SUBW = NOUT / 2;
    const int lane = threadIdx.x & 63;
    const int ll = lane & (SUBW - 1);
    const int dpb = 256 / SUBW;
    const int dst = blockIdx.x * dpb + threadIdx.x / SUBW;
    if (dst >= nnodes) return;
    const int base = lane & ~(SUBW - 1);
    const int beg = offsets[dst], end = offsets[dst + 1];
    float ax = 0.f, ay = 0.f;

    auto rowp = [&](unsigned key) {
        return (const unsigned*)(T + ((size_t)(key & 15) * npad + (key >> 4)) * NOUT);
    };

    for (int i = beg; i < end; i += SUBW) {
        int cnt = min(SUBW, end - i);
        uint2 pl = make_uint2(0u, 0u);
        if (ll < cnt) pl = payload[i + ll];
        int j = 0;
        for (; j + 4 <= cnt; j += 4) {
            unsigned k0 = (unsigned)__shfl((int)pl.x, base + j);
            unsigned k1 = (unsigned)__shfl((int)pl.x, base + j + 1);
            unsigned k2 = (unsigned)__shfl((int)pl.x, base + j + 2);
            unsigned k3 = (unsigned)__shfl((int)pl.x, base + j + 3);
            float n0 = __builtin_bit_cast(float, (unsigned)__shfl((int)pl.y, base + j));
            float n1 = __builtin_bit_cast(float, (unsigned)__shfl((int)pl.y, base + j + 1));
            float n2 = __builtin_bit_cast(float, (unsigned)__shfl((int)pl.y, base + j + 2));
            float n3 = __builtin_bit_cast(float, (unsigned)__shfl((int)pl.y, base + j + 3));
            unsigned v0 = rowp(k0)[ll];
            unsigned v1 = rowp(k1)[ll];
            unsigned v2 = rowp(k2)[ll];
            unsigned v3 = rowp(k3)[ll];
            ax = fmaf(lo16(v0), n0, ax); ay = fmaf(hi16(v0), n0, ay);
            ax = fmaf(lo16(v1), n1, ax); ay = fmaf(hi16(v1), n1, ay);
            ax = fmaf(lo16(v2), n2, ax); ay = fmaf(hi16(v2), n2, ay);
            ax = fmaf(lo16(v3), n3, ax); ay = fmaf(hi16(v3), n3, ay);
        }
        for (; j < cnt; j++) {
            unsigned k = (unsigned)__shfl((int)pl.x, base + j);
            float nm = __builtin_bit_cast(float, (unsigned)__shfl((int)pl.y, base + j));
            unsigned v = rowp(k)[ll];
            ax = fmaf(lo16(v), nm, ax);
            ay = fmaf(hi16(v), nm, ay);
        }
    }
    if (OUTMODE == 0) {
        ((unsigned*)out)[(size_t)dst * SUBW + ll] = pack2(fmaxf(ax, 0.f), fmaxf(ay, 0.f));
    } else {
        if (*flagp) {
            ((unsigned*)out)[(size_t)dst * SUBW + ll] = pack2(ax, ay);
        } else {
            float2 v;
            v.x = ax; v.y = ay;
            ((float2*)out)[(size_t)dst * SUBW + ll] = v;
        }
    }
}

// ---------------- fallback path (chunked + atomics, node-major t) ----------------
template <int NOUT, int AMODE>
__global__ __launch_bounds__(256) void gemm_rel(const void* __restrict__ Asrc,
                                                const unsigned short* __restrict__ Wt,
                                                unsigned short* __restrict__ T, int nnodes,
                                                int rbase, const int* __restrict__ flagp) {
    constexpr int LDA = 136;
    __shared__ unsigned short lA[64 * LDA];
    __shared__ unsigned short lB[NOUT * LDA];
    const int tid = threadIdx.x;
    const int node0 = blockIdx.x * 64;
    const int rel = rbase + blockIdx.y;
    const int Gr = gridDim.y;
    const int flag = (AMODE == 0) ? *flagp : 1;

    for (int i = tid; i < 64 * 16; i += 256) {
        int row = i >> 4, seg = i & 15;
        int node = node0 + row;
        uint4 v = make_uint4(0u, 0u, 0u, 0u);
        if (node < nnodes) {
            if (AMODE == 1) {
                const float* p = (const float*)Asrc + (size_t)node * 128 + seg * 8;
                float4 f0 = ((const float4*)p)[0];
                float4 f1 = ((const float4*)p)[1];
                v.x = pack2(fmaxf(f0.x, 0.f), fmaxf(f0.y, 0.f));
                v.y = pack2(fmaxf(f0.z, 0.f), fmaxf(f0.w, 0.f));
                v.z = pack2(fmaxf(f1.x, 0.f), fmaxf(f1.y, 0.f));
                v.w = pack2(fmaxf(f1.z, 0.f), fmaxf(f1.w, 0.f));
            } else if (flag) {
                v = *(const uint4*)((const unsigned short*)Asrc + (size_t)node * 128 + seg * 8);
            } else {
                const float* p = (const float*)Asrc + (size_t)node * 128 + seg * 8;
                float4 f0 = ((const float4*)p)[0];
                float4 f1 = ((const float4*)p)[1];
                v.x = pack2(f0.x, f0.y);
                v.y = pack2(f0.z, f0.w);
                v.z = pack2(f1.x, f1.y);
                v.w = pack2(f1.z, f1.w);
            }
        }
        *(uint4*)(lA + row * LDA + seg * 8) = v;
    }
    for (int i = tid; i < NOUT * 16; i += 256) {
        int o = i >> 4, seg = i & 15;
        *(uint4*)(lB + o * LDA + seg * 8) =
            *(const uint4*)(Wt + ((size_t)rel * NOUT + o) * 128 + seg * 8);
    }
    __syncthreads();

    const int w = tid >> 6, lane = tid & 63;
    const int quad = lane >> 4, mr = lane & 15;
    constexpr int NT = NOUT / 16;
    f32x4 acc[NT];
#pragma unroll
    for (int t = 0; t < NT; t++) acc[t] = 0.f;
    const unsigned short* pa = lA + (w * 16 + mr) * LDA + quad * 8;
    const unsigned short* pb = lB + mr * LDA + quad * 8;
#pragma unroll
    for (int kk = 0; kk < 4; kk++) {
        bf16x8 a = *(const bf16x8*)(pa + kk * 32);
#pragma unroll
        for (int nt = 0; nt < NT; nt++) {
            bf16x8 b = *(const bf16x8*)(pb + nt * 16 * LDA + kk * 32);
            acc[nt] = __builtin_amdgcn_mfma_f32_16x16x32_bf16(a, b, acc[nt], 0, 0, 0);
        }
    }
#pragma unroll
    for (int nt = 0; nt < NT; nt++)
#pragma unroll
        for (int reg = 0; reg < 4; reg++) {
            int node = node0 + w * 16 + quad * 4 + reg;
            if (node < nnodes)
                T[((size_t)node * Gr + blockIdx.y) * NOUT + nt * 16 + mr] = f2bf(acc[nt][reg]);
        }
}

template <int NOUT>
__global__ void scatter_k(const unsigned short* __restrict__ T, int Gr, int rbase,
                          const void* __restrict__ nrm, const int* __restrict__ flagp,
                          const int* __restrict__ src, const int* __restrict__ dst,
                          const int* __restrict__ et, float* __restrict__ accum, int nedges) {
    constexpr int LPE = NOUT / 2;
    const int flag = *flagp;
    const int epb = 256 / LPE;
    const int sub = threadIdx.x % LPE;
    const int slot = threadIdx.x / LPE;
    for (int e = blockIdx.x * epb + slot; e < nedges; e += gridDim.x * epb) {
        int g = et[e] - rbase;
        if (g < 0 || g >= Gr) continue;
        int s = src[e], d = dst[e];
        float nm = flag ? bf2f(((const unsigned short*)nrm)[e]) : ((const float*)nrm)[e];
        unsigned pv = ((const unsigned*)(T + ((size_t)s * Gr + g) * NOUT))[sub];
        float* p = accum + (size_t)d * NOUT + sub * 2;
        unsafeAtomicAdd(p, lo16(pv) * nm);
        unsafeAtomicAdd(p + 1, hi16(pv) * nm);
    }
}

__global__ void write_out(const float* __restrict__ acc, void* __restrict__ dout, int n,
                          const int* __restrict__ flagp) {
    int flag = *flagp;
    int i = blockIdx.x * 256 + threadIdx.x;
    if (i >= n) return;
    float v = acc[i];
    if (flag) ((unsigned short*)dout)[i] = f2bf(v);
    else      ((float*)dout)[i] = v;
}

extern "C" void kernel_launch(void* const* d_in, const int* in_sizes, int n_in,
                              void* d_out, int out_size, void* d_ws, size_t ws_size,
                              hipStream_t stream) {
    const void* feat = d_in[0];
    const void* norm = d_in[1];
    const void* W1 = d_in[2];
    const void* W2 = d_in[3];
    const int* src = (const int*)d_in[4];
    const int* dst = (const int*)d_in[5];
    const int* et  = (const int*)d_in[6];

    const int nnodes = in_sizes[0] / 128;
    const int nedges = in_sizes[1];

    char* ws = (char*)d_ws;
    size_t off = 0;
    auto alloc = [&](size_t bytes) { size_t o = off; off += (bytes + 255) & ~255ULL; return o; };
    size_t off_flag = alloc(4);
    size_t off_w1t  = alloc((size_t)R_NUM * 128 * 128 * 2);
    size_t off_w2t  = alloc((size_t)R_NUM * 64 * 128 * 2);

    int* flagp = (int*)(ws + off_flag);
    unsigned short* w1t = (unsigned short*)(ws + off_w1t);
    unsigned short* w2t = (unsigned short*)(ws + off_w2t);

    const int gx = (nnodes + 63) / 64;
    const int npad = gx * 64;  // padded node count: uniform store counts in gemm_plane
    constexpr int RPB = 4;     // rels per block (occupancy/refetch sweet spot)

    // fast-path layout
    size_t f_off = off;
    auto falloc = [&](size_t bytes) { size_t o = f_off; f_off += (bytes + 255) & ~255ULL; return o; };
    size_t off_offs = falloc((size_t)(nnodes + 1) * 4);
    size_t off_curs = falloc((size_t)nnodes * 4);
    size_t off_cnt  = falloc((size_t)nnodes * 4);
    size_t off_bsum = falloc(1024 * 4);
    size_t off_boff = falloc(1024 * 4);
    size_t off_pay  = falloc((size_t)nedges * 8);
    size_t off_nbf  = falloc((size_t)nnodes * 128 * 2);  // bf16 node buf: feat pass1, h pass2
    size_t off_t    = falloc((size_t)npad * R_NUM * 128 * 2);
    const int nb = (nnodes + 1023) / 1024;
    bool fast = (f_off <= ws_size) && (nb <= 1024);

    const int ntr = R_NUM * 128 * 128 + R_NUM * 128 * 64;

    detect_dtype<<<1, 256, 0, stream>>>((const unsigned short*)feat, flagp);
    transpose_both<<<(ntr + 255) / 256, 256, 0, stream>>>(W1, W2, w1t, w2t, flagp);

    if (fast) {
        int* offs = (int*)(ws + off_offs);
        int* curs = (int*)(ws + off_curs);
        int* cnt  = (int*)(ws + off_cnt);
        int* bsum = (int*)(ws + off_bsum);
        int* boff = (int*)(ws + off_boff);
        uint2* pay = (uint2*)(ws + off_pay);
        unsigned short* nbf = (unsigned short*)(ws + off_nbf);
        unsigned short* t = (unsigned short*)(ws + off_t);

        hipMemsetAsync(cnt, 0, (size_t)nnodes * 4, stream);
        hist_dst<<<(nedges + 255) / 256, 256, 0, stream>>>(dst, cnt, nedges);
        scan_phase1<<<nb, 256, 0, stream>>>(cnt, bsum, nnodes);
        scan_phase2<<<1, 1024, 0, stream>>>(bsum, boff, nb);
        scan_phase3<<<nb, 256, 0, stream>>>(cnt, boff, offs, curs, nnodes);
        fill_payload<<<(nedges + 255) / 256, 256, 0, stream>>>(src, dst, et, norm, flagp,
                                                               curs, pay, nedges);

        const int n8 = nnodes * 16;
        to_bf16<<<(n8 + 255) / 256, 256, 0, stream>>>(feat, nbf, n8, flagp);

        gemm_plane<128, RPB><<<gx * (R_NUM / RPB), 256, 0, stream>>>(nbf, w1t, t, nnodes, npad);
        gather_seg<128, 0><<<(nnodes + 3) / 4, 256, 0, stream>>>(t, offs, pay, nbf, nnodes, npad,
                                                                 flagp);
        gemm_plane<64, RPB><<<gx * (R_NUM / RPB), 256, 0, stream>>>(nbf, w2t, t, nnodes, npad);
        gather_seg<64, 1><<<(nnodes + 7) / 8, 256, 0, stream>>>(t, offs, pay, d_out, nnodes, npad,
                                                                flagp);
        return;
    }

    // fallback: chunked atomic path
    size_t off_hpre = alloc((size_t)nnodes * 128 * 4);
    size_t off_oacc = alloc((size_t)nnodes * 64 * 4);
    size_t t_cap = (ws_size > off) ? (ws_size - off) : 0;
    auto pick_gr = [&](int ncol) {
        int gr = 0;
        for (int g = 16; g >= 1; g >>= 1)
            if ((size_t)nnodes * g * ncol * 2 <= t_cap) { gr = g; break; }
        return gr;
    };
    int Gr1 = pick_gr(128);
    int Gr2 = pick_gr(64);
    if (Gr1 < 1 || Gr2 < 1) {
        hipMemsetAsync(d_out, 0x42, (size_t)out_size * 2, stream);
        return;
    }
    float* hpre = (float*)(ws + off_hpre);
    float* oacc = (float*)(ws + off_oacc);
    unsigned short* t = (unsigned short*)(ws + off);

    hipMemsetAsync(hpre, 0, (size_t)nnodes * 128 * 4, stream);
    hipMemsetAsync(oacc, 0, (size_t)nnodes * 64 * 4, stream);
    for (int rb = 0; rb < R_NUM; rb += Gr1) {
        gemm_rel<128, 0><<<dim3(gx, Gr1), 256, 0, stream>>>(feat, w1t, t, nnodes, rb, flagp);
        scatter_k<128><<<4096, 256, 0, stream>>>(t, Gr1, rb, norm, flagp, src, dst, et, hpre, nedges);
    }
    for (int rb = 0; rb < R_NUM; rb += Gr2) {
        gemm_rel<64, 1><<<dim3(gx, Gr2), 256, 0, stream>>>(hpre, w2t, t, nnodes, rb, flagp);
        scatter_k<64><<<4096, 256, 0, stream>>>(t, Gr2, rb, norm, flagp, src, dst, et, oacc, nedges);
    }
    int nout = nnodes * 64;
    write_out<<<(nout + 255) / 256, 256, 0, stream>>>(oacc, d_out, nout, flagp);
}

// Round 14
// 347.315 us; speedup vs baseline: 4.3956x; 1.0387x over previous
//
#include <hip/hip_runtime.h>

// RGCN on MI355X — round 21: verified r16 base (360.8us) + two low-risk micro
// levers. (1) Bijective XCD-chunked swizzle of gemm_plane's blockIdx: the 4
// rel-group blocks sharing one A-tile currently round-robin across 4 XCD L2s
// (FETCH 25.8MB = 2x the 12.8MB input proves the refetch); chunked mapping
// makes them co-XCD (T1). (2) gather_seg inner loop widened 4->8 independent
// T-row loads per round: avg degree 16 at ~900cy HBM-random latency means
// 8-deep halves the latency rounds per dst. Same accumulation order ->
// bit-identical results. Everything else verbatim r16.
// Fast path:
//   to_bf16: feat -> nbf; CSR(dst); t1 = nbf@W1 (gemm_plane<128,4>, gx*4);
//   gather1 -> relu -> nbf; t2 = nbf@W2 (gemm_plane<64,4>); gather2 -> d_out.
// Fallback (small ws): chunked atomic path (unchanged).

#define R_NUM 16

typedef __attribute__((ext_vector_type(8))) short bf16x8;
typedef __attribute__((ext_vector_type(4))) float f32x4;

__device__ __forceinline__ float bf2f(unsigned short u) {
    unsigned int x = ((unsigned int)u) << 16;
    return __builtin_bit_cast(float, x);
}
__device__ __forceinline__ unsigned short f2bf(float f) {
    unsigned int x = __builtin_bit_cast(unsigned int, f);
    x += 0x7FFFu + ((x >> 16) & 1u);  // RNE
    return (unsigned short)(x >> 16);
}
__device__ __forceinline__ unsigned pack2(float a, float b) {
    return (unsigned)f2bf(a) | ((unsigned)f2bf(b) << 16);
}
__device__ __forceinline__ float lo16(unsigned v) { return bf2f((unsigned short)(v & 0xFFFF)); }
__device__ __forceinline__ float hi16(unsigned v) { return bf2f((unsigned short)(v >> 16)); }

// Raw 16B global load the compiler cannot sink/remat/delete (r12-proven).
__device__ __forceinline__ bf16x8 gload16(const unsigned short* p) {
    bf16x8 r;
    asm volatile("global_load_dwordx4 %0, %1, off" : "=&v"(r) : "v"(p));
    return r;
}

// Bijective XCD-chunked blockIdx swizzle (m204 formula, any nwg): consecutive
// LOGICAL ids land on the SAME XCD so tile-sharing blocks share an L2.
__device__ __forceinline__ int xcd_swizzle(int bid, int nwg) {
    const int NX = 8;
    int q = nwg / NX, rem = nwg % NX;
    int xcd = bid % NX, pos = bid / NX;
    int base = (xcd < rem) ? xcd * (q + 1) : rem * (q + 1) + (xcd - rem) * q;
    return base + pos;
}

// ---------------- dtype sniffer (fp32 vs bf16 harness inputs) ----------------
__global__ void detect_dtype(const unsigned short* __restrict__ raw, int* flag) {
    __shared__ int tot;
    if (threadIdx.x == 0) tot = 0;
    __syncthreads();
    int c = 0;
    for (int i = threadIdx.x; i < 4096; i += 256) {
        unsigned short u = raw[2 * i];
        int e = (u >> 7) & 0xFF;
        if (e >= 113 && e <= 134) c++;
    }
    atomicAdd(&tot, c);
    __syncthreads();
    if (threadIdx.x == 0) *flag = (tot > 2048) ? 1 : 0;  // 1 => bf16 inputs
}

// Both weight transposes in one launch: W[r][k][o] -> Wt[r][o][k] bf16.
__global__ void transpose_both(const void* __restrict__ W1, const void* __restrict__ W2,
                               unsigned short* __restrict__ w1t, unsigned short* __restrict__ w2t,
                               const int* __restrict__ flagp) {
    const int flag = *flagp;
    const int n1 = R_NUM * 128 * 128;
    const int n2 = R_NUM * 128 * 64;
    int idx = blockIdx.x * 256 + threadIdx.x;
    if (idx < n1) {
        int k = idx % 128, o = (idx / 128) % 128, r = idx / (128 * 128);
        int iin = (r * 128 + k) * 128 + o;
        float v = flag ? bf2f(((const unsigned short*)W1)[iin]) : ((const float*)W1)[iin];
        w1t[idx] = f2bf(v);
    } else if (idx < n1 + n2) {
        int j = idx - n1;
        int k = j % 128, o = (j / 128) % 64, r = j / (128 * 64);
        int iin = (r * 128 + k) * 64 + o;
        float v = flag ? bf2f(((const unsigned short*)W2)[iin]) : ((const float*)W2)[iin];
        w2t[j] = f2bf(v);
    }
}

// Pack node features to bf16 once (n8 = nnodes*16 uint4 segments).
__global__ void to_bf16(const void* __restrict__ in, unsigned short* __restrict__ out, int n8,
                        const int* __restrict__ flagp) {
    int i = blockIdx.x * 256 + threadIdx.x;
    if (i >= n8) return;
    uint4 v;
    if (*flagp) {
        v = ((const uint4*)in)[i];
    } else {
        const float4* p = (const float4*)in + (size_t)i * 2;
        float4 f0 = p[0];
        float4 f1 = p[1];
        v.x = pack2(f0.x, f0.y);
        v.y = pack2(f0.z, f0.w);
        v.z = pack2(f1.x, f1.y);
        v.w = pack2(f1.z, f1.w);
    }
    ((uint4*)out)[i] = v;
}

// ---------------- GEMM: one (64-node tile, RPB rels) per block -------------
// Transposed MFMA: acc = mfma(Wfrag, featfrag) = (feat@W)^T fragments: lane
// (quad,mr) owns node mt*16+mr, cols c*64+w*16+quad*4..+3.
// Per rel: counted vmcnt retires prefetched asm B-loads (leaves prev rel's
// stores in flight) -> MFMA (lA ds_reads + reg B) -> issue B[r+1] -> pack ->
// ds_write lC -> raw barrier(lgkm only) -> contiguous UNCONDITIONAL store
// (fire&forget, wave-uniform count) -> raw barrier(lgkm only).
// T is npad-strided: padding rows land in padding, never on real data.
template <int NOUT, int RPB>
__global__ __launch_bounds__(256, 3) void gemm_plane(const unsigned short* __restrict__ A,
                                                     const unsigned short* __restrict__ Wt,
                                                     unsigned short* __restrict__ T, int nnodes,
                                                     int npad) {
    constexpr int LDA = 136;
    constexpr int LDC = NOUT + 8;
    constexpr int NTC = NOUT / 64;
    constexpr int SEGS = NOUT / 8;
    constexpr int SPT = 64 * SEGS / 256;  // global stores per thread per rel
    constexpr int NGRP = R_NUM / RPB;
    __shared__ unsigned short lA[64 * LDA];  // A-tile, persists all RPB rels
    __shared__ unsigned short lC[64 * LDC];  // C transpose staging
    const int tid = threadIdx.x;
    // XCD-chunked swizzle: the NGRP rel-group blocks of one tile (consecutive
    // logical ids, rel-group fastest) become co-XCD -> A-tile L2 reuse.
    const int bid = xcd_swizzle(blockIdx.x, gridDim.x);
    const int rbase = (bid % NGRP) * RPB;
    const int node0 = (bid / NGRP) * 64;
    const int w = tid >> 6, lane = tid & 63;
    const int quad = lane >> 4, mr = lane & 15;

    // wave-private B row base: row (w*16+mr) of Wt[rel], 16B chunk per quad
    const unsigned short* wbase = Wt + ((size_t)(w * 16 + mr)) * 128 + quad * 8;

    bf16x8 bfr[2][NTC][4];  // double-buffered B frags (static index per unrolled copy)
#pragma unroll
    for (int c = 0; c < NTC; c++)
#pragma unroll
        for (int kk = 0; kk < 4; kk++)
            bfr[0][c][kk] = gload16(wbase + (size_t)(rbase * NOUT + c * 64) * 128 + kk * 32);

    // stage A once: 64 rows x 16 segs of 8 bf16 (uint4), coalesced
    for (int i = tid; i < 64 * 16; i += 256) {
        int row = i >> 4, seg = i & 15;
        int node = node0 + row;
        uint4 v = make_uint4(0u, 0u, 0u, 0u);
        if (node < nnodes) v = *(const uint4*)(A + (size_t)node * 128 + seg * 8);
        *(uint4*)(lA + row * LDA + seg * 8) = v;
    }
    __syncthreads();  // full drain once: A staged
    // rule 18: bfr[0] comes from asm loads the compiler can't track — force
    // the wait + a scheduling fence so no MFMA precedes B[0] landing.
    asm volatile("s_waitcnt vmcnt(0)" ::: "memory");
    __builtin_amdgcn_sched_barrier(0);

#pragma unroll
    for (int rr = 0; rr < RPB; rr++) {
        const int r = rbase + rr;
        // retire B[r] (prefetched last rel); leave prev rel's SPT stores in
        // flight. Counting is exact: EVERY wave issues exactly NTC*4 loads +
        // SPT stores per rel (stores unconditional).
        if (rr > 0) {
            if constexpr (NOUT == 128)
                asm volatile("s_waitcnt vmcnt(4)" ::: "memory");
            else
                asm volatile("s_waitcnt vmcnt(2)" ::: "memory");
            __builtin_amdgcn_sched_barrier(0);
        }

        f32x4 acc[4][NTC];
#pragma unroll
        for (int mt = 0; mt < 4; mt++)
#pragma unroll
            for (int c = 0; c < NTC; c++) acc[mt][c] = 0.f;

#pragma unroll
        for (int kk = 0; kk < 4; kk++) {
            bf16x8 a[4];
#pragma unroll
            for (int mt = 0; mt < 4; mt++)
                a[mt] = *(const bf16x8*)(lA + (mt * 16 + mr) * LDA + kk * 32 + quad * 8);
#pragma unroll
            for (int c = 0; c < NTC; c++)
#pragma unroll
                for (int mt = 0; mt < 4; mt++)
                    acc[mt][c] = __builtin_amdgcn_mfma_f32_16x16x32_bf16(bfr[rr & 1][c][kk], a[mt],
                                                                         acc[mt][c], 0, 0, 0);
        }

        // prefetch B[r+1] (latency hides under pack/stage/store below)
        if (rr + 1 < RPB) {
#pragma unroll
            for (int c = 0; c < NTC; c++)
#pragma unroll
                for (int kk = 0; kk < 4; kk++)
                    bfr[(rr + 1) & 1][c][kk] =
                        gload16(wbase + (size_t)((r + 1) * NOUT + c * 64) * 128 + kk * 32);
        }

        // pack acc -> lC (the transpose), b64 per (mt,c)
#pragma unroll
        for (int mt = 0; mt < 4; mt++)
#pragma unroll
            for (int c = 0; c < NTC; c++) {
                uint2 pv;
                pv.x = pack2(acc[mt][c][0], acc[mt][c][1]);
                pv.y = pack2(acc[mt][c][2], acc[mt][c][3]);
                *(uint2*)(lC + (mt * 16 + mr) * LDC + c * 64 + w * 16 + quad * 4) = pv;
            }

        // raw barrier: lgkm only — stores stay in flight
        asm volatile("s_waitcnt lgkmcnt(0)" ::: "memory");
        __builtin_amdgcn_sched_barrier(0);
        __builtin_amdgcn_s_barrier();
        __builtin_amdgcn_sched_barrier(0);

        // contiguous fire-and-forget store: 64*NOUT*2 B at T[r][node0], npad
        // stride, UNCONDITIONAL (padding rows are zeros, land in padding).
#pragma unroll
        for (int it = 0; it < SPT; it++) {
            int i = it * 256 + tid;
            int row = i / SEGS, seg = i % SEGS;
            *(uint4*)(T + ((size_t)r * npad + node0 + row) * NOUT + seg * 8) =
                *(const uint4*)(lC + row * LDC + seg * 8);
        }

        // raw barrier: lC reads retired (lgkm) before next rel overwrites
        asm volatile("s_waitcnt lgkmcnt(0)" ::: "memory");
        __builtin_amdgcn_sched_barrier(0);
        __builtin_amdgcn_s_barrier();
        __builtin_amdgcn_sched_barrier(0);
    }
}

// ---------------- CSR build ----------------
__global__ void hist_dst(const int* __restrict__ dst, int* __restrict__ counts, int nedges) {
    int e = blockIdx.x * 256 + threadIdx.x;
    if (e < nedges) atomicAdd(&counts[dst[e]], 1);
}

__global__ __launch_bounds__(256) void scan_phase1(const int* __restrict__ counts,
                                                   int* __restrict__ blocksums, int n) {
    __shared__ int red[256];
    int base = blockIdx.x * 1024 + threadIdx.x * 4;
    int s = 0;
#pragma unroll
    for (int j = 0; j < 4; j++) {
        int idx = base + j;
        if (idx < n) s += counts[idx];
    }
    red[threadIdx.x] = s;
    __syncthreads();
    for (int d = 128; d > 0; d >>= 1) {
        if (threadIdx.x < d) red[threadIdx.x] += red[threadIdx.x + d];
        __syncthreads();
    }
    if (threadIdx.x == 0) blocksums[blockIdx.x] = red[0];
}

__global__ __launch_bounds__(1024) void scan_phase2(const int* __restrict__ blocksums,
                                                    int* __restrict__ blockoff, int nb) {
    __shared__ int arr[1024];
    int t = threadIdx.x;
    arr[t] = (t < nb) ? blocksums[t] : 0;
    __syncthreads();
    for (int d = 1; d < 1024; d <<= 1) {
        int v = (t >= d) ? arr[t - d] : 0;
        __syncthreads();
        arr[t] += v;
        __syncthreads();
    }
    if (t < nb) blockoff[t] = (t == 0) ? 0 : arr[t - 1];
}

__global__ __launch_bounds__(256) void scan_phase3(const int* __restrict__ counts,
                                                   const int* __restrict__ blockoff,
                                                   int* __restrict__ offsets,
                                                   int* __restrict__ cursor, int n) {
    __shared__ int tsum[256];
    int base = blockIdx.x * 1024 + threadIdx.x * 4;
    int c[4];
    int s = 0;
#pragma unroll
    for (int j = 0; j < 4; j++) {
        int idx = base + j;
        c[j] = (idx < n) ? counts[idx] : 0;
        s += c[j];
    }
    tsum[threadIdx.x] = s;
    __syncthreads();
    for (int d = 1; d < 256; d <<= 1) {
        int v = (threadIdx.x >= d) ? tsum[threadIdx.x - d] : 0;
        __syncthreads();
        tsum[threadIdx.x] += v;
        __syncthreads();
    }
    int run = blockoff[blockIdx.x] + ((threadIdx.x == 0) ? 0 : tsum[threadIdx.x - 1]);
#pragma unroll
    for (int j = 0; j < 4; j++) {
        int idx = base + j;
        if (idx < n) {
            offsets[idx] = run;
            cursor[idx] = run;
            if (idx == n - 1) offsets[n] = run + c[j];
            run += c[j];
        }
    }
}

__global__ void fill_payload(const int* __restrict__ src, const int* __restrict__ dst,
                             const int* __restrict__ et, const void* __restrict__ nrm,
                             const int* __restrict__ flagp, int* __restrict__ cursor,
                             uint2* __restrict__ payload, int nedges) {
    int e = blockIdx.x * 256 + threadIdx.x;
    if (e >= nedges) return;
    int flag = *flagp;
    float nm = flag ? bf2f(((const unsigned short*)nrm)[e]) : ((const float*)nrm)[e];
    int pos = atomicAdd(&cursor[dst[e]], 1);
    uint2 pl;
    pl.x = ((unsigned)src[e] << 4) | (unsigned)(et[e] & 15);
    pl.y = __builtin_bit_cast(unsigned, nm);
    payload[pos] = pl;
}

// ---------------- dst-centric gather (atomic-free) ----------------
// T is rel-major, npad-strided: row = T[(et*npad + src)*NOUT].
// Inner loop is 8-deep (8 independent T-row loads in flight before the fmaf
// chain) to halve HBM-random latency rounds at avg degree 16.
template <int NOUT, int OUTMODE>
__global__ __launch_bounds__(256) void gather_seg(const unsigned short* __restrict__ T,
                                                  const int* __restrict__ offsets,
                                                  const uint2* __restrict__ payload,
                                                  void* __restrict__ out, int nnodes, int npad,
                                                  const int* __restrict__ flagp) {
    constexpr int SUBW = NOUT / 2;
    const int lane = threadIdx.x & 63;
    const int ll = lane & (SUBW - 1);
    const int dpb = 256 / SUBW;
    const int dst = blockIdx.x * dpb + threadIdx.x / SUBW;
    if (dst >= nnodes) return;
    const int base = lane & ~(SUBW - 1);
    const int beg = offsets[dst], end = offsets[dst + 1];
    float ax = 0.f, ay = 0.f;

    auto rowp = [&](unsigned key) {
        return (const unsigned*)(T + ((size_t)(key & 15) * npad + (key >> 4)) * NOUT);
    };

    for (int i = beg; i < end; i += SUBW) {
        int cnt = min(SUBW, end - i);
        uint2 pl = make_uint2(0u, 0u);
        if (ll < cnt) pl = payload[i + ll];
        int j = 0;
        for (; j + 8 <= cnt; j += 8) {
            unsigned k[8];
            float n[8];
            unsigned v[8];
#pragma unroll
            for (int u = 0; u < 8; u++) {
                k[u] = (unsigned)__shfl((int)pl.x, base + j + u);
                n[u] = __builtin_bit_cast(float, (unsigned)__shfl((int)pl.y, base + j + u));
            }
#pragma unroll
            for (int u = 0; u < 8; u++) v[u] = rowp(k[u])[ll];
#pragma unroll
            for (int u = 0; u < 8; u++) {
                ax = fmaf(lo16(v[u]), n[u], ax);
                ay = fmaf(hi16(v[u]), n[u], ay);
            }
        }
        for (; j + 4 <= cnt; j += 4) {
            unsigned k0 = (unsigned)__shfl((int)pl.x, base + j);
            unsigned k1 = (unsigned)__shfl((int)pl.x, base + j + 1);
            unsigned k2 = (unsigned)__shfl((int)pl.x, base + j + 2);
            unsigned k3 = (unsigned)__shfl((int)pl.x, base + j + 3);
            float n0 = __builtin_bit_cast(float, (unsigned)__shfl((int)pl.y, base + j));
            float n1 = __builtin_bit_cast(float, (unsigned)__shfl((int)pl.y, base + j + 1));
            float n2 = __builtin_bit_cast(float, (unsigned)__shfl((int)pl.y, base + j + 2));
            float n3 = __builtin_bit_cast(float, (unsigned)__shfl((int)pl.y, base + j + 3));
            unsigned v0 = rowp(k0)[ll];
            unsigned v1 = rowp(k1)[ll];
            unsigned v2 = rowp(k2)[ll];
            unsigned v3 = rowp(k3)[ll];
            ax = fmaf(lo16(v0), n0, ax); ay = fmaf(hi16(v0), n0, ay);
            ax = fmaf(lo16(v1), n1, ax); ay = fmaf(hi16(v1), n1, ay);
            ax = fmaf(lo16(v2), n2, ax); ay = fmaf(hi16(v2), n2, ay);
            ax = fmaf(lo16(v3), n3, ax); ay = fmaf(hi16(v3), n3, ay);
        }
        for (; j < cnt; j++) {
            unsigned k = (unsigned)__shfl((int)pl.x, base + j);
            float nm = __builtin_bit_cast(float, (unsigned)__shfl((int)pl.y, base + j));
            unsigned v = rowp(k)[ll];
            ax = fmaf(lo16(v), nm, ax);
            ay = fmaf(hi16(v), nm, ay);
        }
    }
    if (OUTMODE == 0) {
        ((unsigned*)out)[(size_t)dst * SUBW + ll] = pack2(fmaxf(ax, 0.f), fmaxf(ay, 0.f));
    } else {
        if (*flagp) {
            ((unsigned*)out)[(size_t)dst * SUBW + ll] = pack2(ax, ay);
        } else {
            float2 v;
            v.x = ax; v.y = ay;
            ((float2*)out)[(size_t)dst * SUBW + ll] = v;
        }
    }
}

// ---------------- fallback path (chunked + atomics, node-major t) ----------------
template <int NOUT, int AMODE>
__global__ __launch_bounds__(256) void gemm_rel(const void* __restrict__ Asrc,
                                                const unsigned short* __restrict__ Wt,
                                                unsigned short* __restrict__ T, int nnodes,
                                                int rbase, const int* __restrict__ flagp) {
    constexpr int LDA = 136;
    __shared__ unsigned short lA[64 * LDA];
    __shared__ unsigned short lB[NOUT * LDA];
    const int tid = threadIdx.x;
    const int node0 = blockIdx.x * 64;
    const int rel = rbase + blockIdx.y;
    const int Gr = gridDim.y;
    const int flag = (AMODE == 0) ? *flagp : 1;

    for (int i = tid; i < 64 * 16; i += 256) {
        int row = i >> 4, seg = i & 15;
        int node = node0 + row;
        uint4 v = make_uint4(0u, 0u, 0u, 0u);
        if (node < nnodes) {
            if (AMODE == 1) {
                const float* p = (const float*)Asrc + (size_t)node * 128 + seg * 8;
                float4 f0 = ((const float4*)p)[0];
                float4 f1 = ((const float4*)p)[1];
                v.x = pack2(fmaxf(f0.x, 0.f), fmaxf(f0.y, 0.f));
                v.y = pack2(fmaxf(f0.z, 0.f), fmaxf(f0.w, 0.f));
                v.z = pack2(fmaxf(f1.x, 0.f), fmaxf(f1.y, 0.f));
                v.w = pack2(fmaxf(f1.z, 0.f), fmaxf(f1.w, 0.f));
            } else if (flag) {
                v = *(const uint4*)((const unsigned short*)Asrc + (size_t)node * 128 + seg * 8);
            } else {
                const float* p = (const float*)Asrc + (size_t)node * 128 + seg * 8;
                float4 f0 = ((const float4*)p)[0];
                float4 f1 = ((const float4*)p)[1];
                v.x = pack2(f0.x, f0.y);
                v.y = pack2(f0.z, f0.w);
                v.z = pack2(f1.x, f1.y);
                v.w = pack2(f1.z, f1.w);
            }
        }
        *(uint4*)(lA + row * LDA + seg * 8) = v;
    }
    for (int i = tid; i < NOUT * 16; i += 256) {
        int o = i >> 4, seg = i & 15;
        *(uint4*)(lB + o * LDA + seg * 8) =
            *(const uint4*)(Wt + ((size_t)rel * NOUT + o) * 128 + seg * 8);
    }
    __syncthreads();

    const int w = tid >> 6, lane = tid & 63;
    const int quad = lane >> 4, mr = lane & 15;
    constexpr int NT = NOUT / 16;
    f32x4 acc[NT];
#pragma unroll
    for (int t = 0; t < NT; t++) acc[t] = 0.f;
    const unsigned short* pa = lA + (w * 16 + mr) * LDA + quad * 8;
    const unsigned short* pb = lB + mr * LDA + quad * 8;
#pragma unroll
    for (int kk = 0; kk < 4; kk++) {
        bf16x8 a = *(const bf16x8*)(pa + kk * 32);
#pragma unroll
        for (int nt = 0; nt < NT; nt++) {
            bf16x8 b = *(const bf16x8*)(pb + nt * 16 * LDA + kk * 32);
            acc[nt] = __builtin_amdgcn_mfma_f32_16x16x32_bf16(a, b, acc[nt], 0, 0, 0);
        }
    }
#pragma unroll
    for (int nt = 0; nt < NT; nt++)
#pragma unroll
        for (int reg = 0; reg < 4; reg++) {
            int node = node0 + w * 16 + quad * 4 + reg;
            if (node < nnodes)
                T[((size_t)node * Gr + blockIdx.y) * NOUT + nt * 16 + mr] = f2bf(acc[nt][reg]);
        }
}

template <int NOUT>
__global__ void scatter_k(const unsigned short* __restrict__ T, int Gr, int rbase,
                          const void* __restrict__ nrm, const int* __restrict__ flagp,
                          const int* __restrict__ src, const int* __restrict__ dst,
                          const int* __restrict__ et, float* __restrict__ accum, int nedges) {
    constexpr int LPE = NOUT / 2;
    const int flag = *flagp;
    const int epb = 256 / LPE;
    const int sub = threadIdx.x % LPE;
    const int slot = threadIdx.x / LPE;
    for (int e = blockIdx.x * epb + slot; e < nedges; e += gridDim.x * epb) {
        int g = et[e] - rbase;
        if (g < 0 || g >= Gr) continue;
        int s = src[e], d = dst[e];
        float nm = flag ? bf2f(((const unsigned short*)nrm)[e]) : ((const float*)nrm)[e];
        unsigned pv = ((const unsigned*)(T + ((size_t)s * Gr + g) * NOUT))[sub];
        float* p = accum + (size_t)d * NOUT + sub * 2;
        unsafeAtomicAdd(p, lo16(pv) * nm);
        unsafeAtomicAdd(p + 1, hi16(pv) * nm);
    }
}

__global__ void write_out(const float* __restrict__ acc, void* __restrict__ dout, int n,
                          const int* __restrict__ flagp) {
    int flag = *flagp;
    int i = blockIdx.x * 256 + threadIdx.x;
    if (i >= n) return;
    float v = acc[i];
    if (flag) ((unsigned short*)dout)[i] = f2bf(v);
    else      ((float*)dout)[i] = v;
}

extern "C" void kernel_launch(void* const* d_in, const int* in_sizes, int n_in,
                              void* d_out, int out_size, void* d_ws, size_t ws_size,
                              hipStream_t stream) {
    const void* feat = d_in[0];
    const void* norm = d_in[1];
    const void* W1 = d_in[2];
    const void* W2 = d_in[3];
    const int* src = (const int*)d_in[4];
    const int* dst = (const int*)d_in[5];
    const int* et  = (const int*)d_in[6];

    const int nnodes = in_sizes[0] / 128;
    const int nedges = in_sizes[1];

    char* ws = (char*)d_ws;
    size_t off = 0;
    auto alloc = [&](size_t bytes) { size_t o = off; off += (bytes + 255) & ~255ULL; return o; };
    size_t off_flag = alloc(4);
    size_t off_w1t  = alloc((size_t)R_NUM * 128 * 128 * 2);
    size_t off_w2t  = alloc((size_t)R_NUM * 64 * 128 * 2);

    int* flagp = (int*)(ws + off_flag);
    unsigned short* w1t = (unsigned short*)(ws + off_w1t);
    unsigned short* w2t = (unsigned short*)(ws + off_w2t);

    const int gx = (nnodes + 63) / 64;
    const int npad = gx * 64;  // padded node count: uniform store counts in gemm_plane
    constexpr int RPB = 4;     // rels per block (occupancy/refetch sweet spot)

    // fast-path layout
    size_t f_off = off;
    auto falloc = [&](size_t bytes) { size_t o = f_off; f_off += (bytes + 255) & ~255ULL; return o; };
    size_t off_offs = falloc((size_t)(nnodes + 1) * 4);
    size_t off_curs = falloc((size_t)nnodes * 4);
    size_t off_cnt  = falloc((size_t)nnodes * 4);
    size_t off_bsum = falloc(1024 * 4);
    size_t off_boff = falloc(1024 * 4);
    size_t off_pay  = falloc((size_t)nedges * 8);
    size_t off_nbf  = falloc((size_t)nnodes * 128 * 2);  // bf16 node buf: feat pass1, h pass2
    size_t off_t    = falloc((size_t)npad * R_NUM * 128 * 2);
    const int nb = (nnodes + 1023) / 1024;
    bool fast = (f_off <= ws_size) && (nb <= 1024);

    const int ntr = R_NUM * 128 * 128 + R_NUM * 128 * 64;

    detect_dtype<<<1, 256, 0, stream>>>((const unsigned short*)feat, flagp);
    transpose_both<<<(ntr + 255) / 256, 256, 0, stream>>>(W1, W2, w1t, w2t, flagp);

    if (fast) {
        int* offs = (int*)(ws + off_offs);
        int* curs = (int*)(ws + off_curs);
        int* cnt  = (int*)(ws + off_cnt);
        int* bsum = (int*)(ws + off_bsum);
        int* boff = (int*)(ws + off_boff);
        uint2* pay = (uint2*)(ws + off_pay);
        unsigned short* nbf = (unsigned short*)(ws + off_nbf);
        unsigned short* t = (unsigned short*)(ws + off_t);

        hipMemsetAsync(cnt, 0, (size_t)nnodes * 4, stream);
        hist_dst<<<(nedges + 255) / 256, 256, 0, stream>>>(dst, cnt, nedges);
        scan_phase1<<<nb, 256, 0, stream>>>(cnt, bsum, nnodes);
        scan_phase2<<<1, 1024, 0, stream>>>(bsum, boff, nb);
        scan_phase3<<<nb, 256, 0, stream>>>(cnt, boff, offs, curs, nnodes);
        fill_payload<<<(nedges + 255) / 256, 256, 0, stream>>>(src, dst, et, norm, flagp,
                                                               curs, pay, nedges);

        const int n8 = nnodes * 16;
        to_bf16<<<(n8 + 255) / 256, 256, 0, stream>>>(feat, nbf, n8, flagp);

        gemm_plane<128, RPB><<<gx * (R_NUM / RPB), 256, 0, stream>>>(nbf, w1t, t, nnodes, npad);
        gather_seg<128, 0><<<(nnodes + 3) / 4, 256, 0, stream>>>(t, offs, pay, nbf, nnodes, npad,
                                                                 flagp);
        gemm_plane<64, RPB><<<gx * (R_NUM / RPB), 256, 0, stream>>>(nbf, w2t, t, nnodes, npad);
        gather_seg<64, 1><<<(nnodes + 7) / 8, 256, 0, stream>>>(t, offs, pay, d_out, nnodes, npad,
                                                                flagp);
        return;
    }

    // fallback: chunked atomic path
    size_t off_hpre = alloc((size_t)nnodes * 128 * 4);
    size_t off_oacc = alloc((size_t)nnodes * 64 * 4);
    size_t t_cap = (ws_size > off) ? (ws_size - off) : 0;
    auto pick_gr = [&](int ncol) {
        int gr = 0;
        for (int g = 16; g >= 1; g >>= 1)
            if ((size_t)nnodes * g * ncol * 2 <= t_cap) { gr = g; break; }
        return gr;
    };
    int Gr1 = pick_gr(128);
    int Gr2 = pick_gr(64);
    if (Gr1 < 1 || Gr2 < 1) {
        hipMemsetAsync(d_out, 0x42, (size_t)out_size * 2, stream);
        return;
    }
    float* hpre = (float*)(ws + off_hpre);
    float* oacc = (float*)(ws + off_oacc);
    unsigned short* t = (unsigned short*)(ws + off);

    hipMemsetAsync(hpre, 0, (size_t)nnodes * 128 * 4, stream);
    hipMemsetAsync(oacc, 0, (size_t)nnodes * 64 * 4, stream);
    for (int rb = 0; rb < R_NUM; rb += Gr1) {
        gemm_rel<128, 0><<<dim3(gx, Gr1), 256, 0, stream>>>(feat, w1t, t, nnodes, rb, flagp);
        scatter_k<128><<<4096, 256, 0, stream>>>(t, Gr1, rb, norm, flagp, src, dst, et, hpre, nedges);
    }
    for (int rb = 0; rb < R_NUM; rb += Gr2) {
        gemm_rel<64, 1><<<dim3(gx, Gr2), 256, 0, stream>>>(hpre, w2t, t, nnodes, rb, flagp);
        scatter_k<64><<<4096, 256, 0, stream>>>(t, Gr2, rb, norm, flagp, src, dst, et, oacc, nedges);
    }
    int nout = nnodes * 64;
    write_out<<<(nout + 255) / 256, 256, 0, stream>>>(oacc, d_out, nout, flagp);
}

// Round 15
// 345.705 us; speedup vs baseline: 4.4160x; 1.0047x over previous
//
#include <hip/hip_runtime.h>

// RGCN on MI355X — round 22: r21 base (347.3us, best) + 16-deep gather ILP.
// r21 verified: XCD-chunked swizzle cut gemm1 FETCH 25.8->9.7MB, dur 73->69us
// (~92% of the session's demonstrated ~3.3TB/s store-path ceiling — gemm1
// lever closed). Remaining bulk is the gathers: degree ~Poisson(16) and the
// deepest ILP tier was 8 -> a typical dst pays TWO dependent latency rounds.
// r22 adds a 16-deep first tier (whole typical edge list in flight in one
// round; k/n/v arrays statically indexed per rule #20; 8/4/1 tails keep the
// accumulation order -> bit-identical results). Everything else verbatim r21.
// Fast path:
//   to_bf16: feat -> nbf; CSR(dst); t1 = nbf@W1 (gemm_plane<128,4>, gx*4,
//   XCD-swizzled); gather1 -> relu -> nbf; t2 = nbf@W2; gather2 -> d_out.
// Fallback (small ws): chunked atomic path (unchanged).

#define R_NUM 16

typedef __attribute__((ext_vector_type(8))) short bf16x8;
typedef __attribute__((ext_vector_type(4))) float f32x4;

__device__ __forceinline__ float bf2f(unsigned short u) {
    unsigned int x = ((unsigned int)u) << 16;
    return __builtin_bit_cast(float, x);
}
__device__ __forceinline__ unsigned short f2bf(float f) {
    unsigned int x = __builtin_bit_cast(unsigned int, f);
    x += 0x7FFFu + ((x >> 16) & 1u);  // RNE
    return (unsigned short)(x >> 16);
}
__device__ __forceinline__ unsigned pack2(float a, float b) {
    return (unsigned)f2bf(a) | ((unsigned)f2bf(b) << 16);
}
__device__ __forceinline__ float lo16(unsigned v) { return bf2f((unsigned short)(v & 0xFFFF)); }
__device__ __forceinline__ float hi16(unsigned v) { return bf2f((unsigned short)(v >> 16)); }

// Raw 16B global load the compiler cannot sink/remat/delete (r12-proven).
__device__ __forceinline__ bf16x8 gload16(const unsigned short* p) {
    bf16x8 r;
    asm volatile("global_load_dwordx4 %0, %1, off" : "=&v"(r) : "v"(p));
    return r;
}

// Bijective XCD-chunked blockIdx swizzle (m204 formula, any nwg): consecutive
// LOGICAL ids land on the SAME XCD so tile-sharing blocks share an L2.
__device__ __forceinline__ int xcd_swizzle(int bid, int nwg) {
    const int NX = 8;
    int q = nwg / NX, rem = nwg % NX;
    int xcd = bid % NX, pos = bid / NX;
    int base = (xcd < rem) ? xcd * (q + 1) : rem * (q + 1) + (xcd - rem) * q;
    return base + pos;
}

// ---------------- dtype sniffer (fp32 vs bf16 harness inputs) ----------------
__global__ void detect_dtype(const unsigned short* __restrict__ raw, int* flag) {
    __shared__ int tot;
    if (threadIdx.x == 0) tot = 0;
    __syncthreads();
    int c = 0;
    for (int i = threadIdx.x; i < 4096; i += 256) {
        unsigned short u = raw[2 * i];
        int e = (u >> 7) & 0xFF;
        if (e >= 113 && e <= 134) c++;
    }
    atomicAdd(&tot, c);
    __syncthreads();
    if (threadIdx.x == 0) *flag = (tot > 2048) ? 1 : 0;  // 1 => bf16 inputs
}

// Both weight transposes in one launch: W[r][k][o] -> Wt[r][o][k] bf16.
__global__ void transpose_both(const void* __restrict__ W1, const void* __restrict__ W2,
                               unsigned short* __restrict__ w1t, unsigned short* __restrict__ w2t,
                               const int* __restrict__ flagp) {
    const int flag = *flagp;
    const int n1 = R_NUM * 128 * 128;
    const int n2 = R_NUM * 128 * 64;
    int idx = blockIdx.x * 256 + threadIdx.x;
    if (idx < n1) {
        int k = idx % 128, o = (idx / 128) % 128, r = idx / (128 * 128);
        int iin = (r * 128 + k) * 128 + o;
        float v = flag ? bf2f(((const unsigned short*)W1)[iin]) : ((const float*)W1)[iin];
        w1t[idx] = f2bf(v);
    } else if (idx < n1 + n2) {
        int j = idx - n1;
        int k = j % 128, o = (j / 128) % 64, r = j / (128 * 64);
        int iin = (r * 128 + k) * 64 + o;
        float v = flag ? bf2f(((const unsigned short*)W2)[iin]) : ((const float*)W2)[iin];
        w2t[j] = f2bf(v);
    }
}

// Pack node features to bf16 once (n8 = nnodes*16 uint4 segments).
__global__ void to_bf16(const void* __restrict__ in, unsigned short* __restrict__ out, int n8,
                        const int* __restrict__ flagp) {
    int i = blockIdx.x * 256 + threadIdx.x;
    if (i >= n8) return;
    uint4 v;
    if (*flagp) {
        v = ((const uint4*)in)[i];
    } else {
        const float4* p = (const float4*)in + (size_t)i * 2;
        float4 f0 = p[0];
        float4 f1 = p[1];
        v.x = pack2(f0.x, f0.y);
        v.y = pack2(f0.z, f0.w);
        v.z = pack2(f1.x, f1.y);
        v.w = pack2(f1.z, f1.w);
    }
    ((uint4*)out)[i] = v;
}

// ---------------- GEMM: one (64-node tile, RPB rels) per block -------------
// Transposed MFMA: acc = mfma(Wfrag, featfrag) = (feat@W)^T fragments: lane
// (quad,mr) owns node mt*16+mr, cols c*64+w*16+quad*4..+3.
// Per rel: counted vmcnt retires prefetched asm B-loads (leaves prev rel's
// stores in flight) -> MFMA (lA ds_reads + reg B) -> issue B[r+1] -> pack ->
// ds_write lC -> raw barrier(lgkm only) -> contiguous UNCONDITIONAL store
// (fire&forget, wave-uniform count) -> raw barrier(lgkm only).
// T is npad-strided: padding rows land in padding, never on real data.
template <int NOUT, int RPB>
__global__ __launch_bounds__(256, 3) void gemm_plane(const unsigned short* __restrict__ A,
                                                     const unsigned short* __restrict__ Wt,
                                                     unsigned short* __restrict__ T, int nnodes,
                                                     int npad) {
    constexpr int LDA = 136;
    constexpr int LDC = NOUT + 8;
    constexpr int NTC = NOUT / 64;
    constexpr int SEGS = NOUT / 8;
    constexpr int SPT = 64 * SEGS / 256;  // global stores per thread per rel
    constexpr int NGRP = R_NUM / RPB;
    __shared__ unsigned short lA[64 * LDA];  // A-tile, persists all RPB rels
    __shared__ unsigned short lC[64 * LDC];  // C transpose staging
    const int tid = threadIdx.x;
    // XCD-chunked swizzle: the NGRP rel-group blocks of one tile (consecutive
    // logical ids, rel-group fastest) become co-XCD -> A-tile L2 reuse.
    const int bid = xcd_swizzle(blockIdx.x, gridDim.x);
    const int rbase = (bid % NGRP) * RPB;
    const int node0 = (bid / NGRP) * 64;
    const int w = tid >> 6, lane = tid & 63;
    const int quad = lane >> 4, mr = lane & 15;

    // wave-private B row base: row (w*16+mr) of Wt[rel], 16B chunk per quad
    const unsigned short* wbase = Wt + ((size_t)(w * 16 + mr)) * 128 + quad * 8;

    bf16x8 bfr[2][NTC][4];  // double-buffered B frags (static index per unrolled copy)
#pragma unroll
    for (int c = 0; c < NTC; c++)
#pragma unroll
        for (int kk = 0; kk < 4; kk++)
            bfr[0][c][kk] = gload16(wbase + (size_t)(rbase * NOUT + c * 64) * 128 + kk * 32);

    // stage A once: 64 rows x 16 segs of 8 bf16 (uint4), coalesced
    for (int i = tid; i < 64 * 16; i += 256) {
        int row = i >> 4, seg = i & 15;
        int node = node0 + row;
        uint4 v = make_uint4(0u, 0u, 0u, 0u);
        if (node < nnodes) v = *(const uint4*)(A + (size_t)node * 128 + seg * 8);
        *(uint4*)(lA + row * LDA + seg * 8) = v;
    }
    __syncthreads();  // full drain once: A staged
    // rule 18: bfr[0] comes from asm loads the compiler can't track — force
    // the wait + a scheduling fence so no MFMA precedes B[0] landing.
    asm volatile("s_waitcnt vmcnt(0)" ::: "memory");
    __builtin_amdgcn_sched_barrier(0);

#pragma unroll
    for (int rr = 0; rr < RPB; rr++) {
        const int r = rbase + rr;
        // retire B[r] (prefetched last rel); leave prev rel's SPT stores in
        // flight. Counting is exact: EVERY wave issues exactly NTC*4 loads +
        // SPT stores per rel (stores unconditional).
        if (rr > 0) {
            if constexpr (NOUT == 128)
                asm volatile("s_waitcnt vmcnt(4)" ::: "memory");
            else
                asm volatile("s_waitcnt vmcnt(2)" ::: "memory");
            __builtin_amdgcn_sched_barrier(0);
        }

        f32x4 acc[4][NTC];
#pragma unroll
        for (int mt = 0; mt < 4; mt++)
#pragma unroll
            for (int c = 0; c < NTC; c++) acc[mt][c] = 0.f;

#pragma unroll
        for (int kk = 0; kk < 4; kk++) {
            bf16x8 a[4];
#pragma unroll
            for (int mt = 0; mt < 4; mt++)
                a[mt] = *(const bf16x8*)(lA + (mt * 16 + mr) * LDA + kk * 32 + quad * 8);
#pragma unroll
            for (int c = 0; c < NTC; c++)
#pragma unroll
                for (int mt = 0; mt < 4; mt++)
                    acc[mt][c] = __builtin_amdgcn_mfma_f32_16x16x32_bf16(bfr[rr & 1][c][kk], a[mt],
                                                                         acc[mt][c], 0, 0, 0);
        }

        // prefetch B[r+1] (latency hides under pack/stage/store below)
        if (rr + 1 < RPB) {
#pragma unroll
            for (int c = 0; c < NTC; c++)
#pragma unroll
                for (int kk = 0; kk < 4; kk++)
                    bfr[(rr + 1) & 1][c][kk] =
                        gload16(wbase + (size_t)((r + 1) * NOUT + c * 64) * 128 + kk * 32);
        }

        // pack acc -> lC (the transpose), b64 per (mt,c)
#pragma unroll
        for (int mt = 0; mt < 4; mt++)
#pragma unroll
            for (int c = 0; c < NTC; c++) {
                uint2 pv;
                pv.x = pack2(acc[mt][c][0], acc[mt][c][1]);
                pv.y = pack2(acc[mt][c][2], acc[mt][c][3]);
                *(uint2*)(lC + (mt * 16 + mr) * LDC + c * 64 + w * 16 + quad * 4) = pv;
            }

        // raw barrier: lgkm only — stores stay in flight
        asm volatile("s_waitcnt lgkmcnt(0)" ::: "memory");
        __builtin_amdgcn_sched_barrier(0);
        __builtin_amdgcn_s_barrier();
        __builtin_amdgcn_sched_barrier(0);

        // contiguous fire-and-forget store: 64*NOUT*2 B at T[r][node0], npad
        // stride, UNCONDITIONAL (padding rows are zeros, land in padding).
#pragma unroll
        for (int it = 0; it < SPT; it++) {
            int i = it * 256 + tid;
            int row = i / SEGS, seg = i % SEGS;
            *(uint4*)(T + ((size_t)r * npad + node0 + row) * NOUT + seg * 8) =
                *(const uint4*)(lC + row * LDC + seg * 8);
        }

        // raw barrier: lC reads retired (lgkm) before next rel overwrites
        asm volatile("s_waitcnt lgkmcnt(0)" ::: "memory");
        __builtin_amdgcn_sched_barrier(0);
        __builtin_amdgcn_s_barrier();
        __builtin_amdgcn_sched_barrier(0);
    }
}

// ---------------- CSR build ----------------
__global__ void hist_dst(const int* __restrict__ dst, int* __restrict__ counts, int nedges) {
    int e = blockIdx.x * 256 + threadIdx.x;
    if (e < nedges) atomicAdd(&counts[dst[e]], 1);
}

__global__ __launch_bounds__(256) void scan_phase1(const int* __restrict__ counts,
                                                   int* __restrict__ blocksums, int n) {
    __shared__ int red[256];
    int base = blockIdx.x * 1024 + threadIdx.x * 4;
    int s = 0;
#pragma unroll
    for (int j = 0; j < 4; j++) {
        int idx = base + j;
        if (idx < n) s += counts[idx];
    }
    red[threadIdx.x] = s;
    __syncthreads();
    for (int d = 128; d > 0; d >>= 1) {
        if (threadIdx.x < d) red[threadIdx.x] += red[threadIdx.x + d];
        __syncthreads();
    }
    if (threadIdx.x == 0) blocksums[blockIdx.x] = red[0];
}

__global__ __launch_bounds__(1024) void scan_phase2(const int* __restrict__ blocksums,
                                                    int* __restrict__ blockoff, int nb) {
    __shared__ int arr[1024];
    int t = threadIdx.x;
    arr[t] = (t < nb) ? blocksums[t] : 0;
    __syncthreads();
    for (int d = 1; d < 1024; d <<= 1) {
        int v = (t >= d) ? arr[t - d] : 0;
        __syncthreads();
        arr[t] += v;
        __syncthreads();
    }
    if (t < nb) blockoff[t] = (t == 0) ? 0 : arr[t - 1];
}

__global__ __launch_bounds__(256) void scan_phase3(const int* __restrict__ counts,
                                                   const int* __restrict__ blockoff,
                                                   int* __restrict__ offsets,
                                                   int* __restrict__ cursor, int n) {
    __shared__ int tsum[256];
    int base = blockIdx.x * 1024 + threadIdx.x * 4;
    int c[4];
    int s = 0;
#pragma unroll
    for (int j = 0; j < 4; j++) {
        int idx = base + j;
        c[j] = (idx < n) ? counts[idx] : 0;
        s += c[j];
    }
    tsum[threadIdx.x] = s;
    __syncthreads();
    for (int d = 1; d < 256; d <<= 1) {
        int v = (threadIdx.x >= d) ? tsum[threadIdx.x - d] : 0;
        __syncthreads();
        tsum[threadIdx.x] += v;
        __syncthreads();
    }
    int run = blockoff[blockIdx.x] + ((threadIdx.x == 0) ? 0 : tsum[threadIdx.x - 1]);
#pragma unroll
    for (int j = 0; j < 4; j++) {
        int idx = base + j;
        if (idx < n) {
            offsets[idx] = run;
            cursor[idx] = run;
            if (idx == n - 1) offsets[n] = run + c[j];
            run += c[j];
        }
    }
}

__global__ void fill_payload(const int* __restrict__ src, const int* __restrict__ dst,
                             const int* __restrict__ et, const void* __restrict__ nrm,
                             const int* __restrict__ flagp, int* __restrict__ cursor,
                             uint2* __restrict__ payload, int nedges) {
    int e = blockIdx.x * 256 + threadIdx.x;
    if (e >= nedges) return;
    int flag = *flagp;
    float nm = flag ? bf2f(((const unsigned short*)nrm)[e]) : ((const float*)nrm)[e];
    int pos = atomicAdd(&cursor[dst[e]], 1);
    uint2 pl;
    pl.x = ((unsigned)src[e] << 4) | (unsigned)(et[e] & 15);
    pl.y = __builtin_bit_cast(unsigned, nm);
    payload[pos] = pl;
}

// ---------------- dst-centric gather (atomic-free) ----------------
// T is rel-major, npad-strided: row = T[(et*npad + src)*NOUT].
// Inner loop: 16-deep first tier (whole Poisson(16) edge list in flight in
// ONE latency round), then 8/4/1 tails (same accumulation order).
template <int NOUT, int OUTMODE>
__global__ __launch_bounds__(256) void gather_seg(const unsigned short* __restrict__ T,
                                                  const int* __restrict__ offsets,
                                                  const uint2* __restrict__ payload,
                                                  void* __restrict__ out, int nnodes, int npad,
                                                  const int* __restrict__ flagp) {
    constexpr int SUBW = NOUT / 2;
    const int lane = threadIdx.x & 63;
    const int ll = lane & (SUBW - 1);
    const int dpb = 256 / SUBW;
    const int dst = blockIdx.x * dpb + threadIdx.x / SUBW;
    if (dst >= nnodes) return;
    const int base = lane & ~(SUBW - 1);
    const int beg = offsets[dst], end = offsets[dst + 1];
    float ax = 0.f, ay = 0.f;

    auto rowp = [&](unsigned key) {
        return (const unsigned*)(T + ((size_t)(key & 15) * npad + (key >> 4)) * NOUT);
    };

    for (int i = beg; i < end; i += SUBW) {
        int cnt = min(SUBW, end - i);
        uint2 pl = make_uint2(0u, 0u);
        if (ll < cnt) pl = payload[i + ll];
        int j = 0;
        for (; j + 16 <= cnt; j += 16) {
            unsigned k[16];
            float n[16];
            unsigned v[16];
#pragma unroll
            for (int u = 0; u < 16; u++) {
                k[u] = (unsigned)__shfl((int)pl.x, base + j + u);
                n[u] = __builtin_bit_cast(float, (unsigned)__shfl((int)pl.y, base + j + u));
            }
#pragma unroll
            for (int u = 0; u < 16; u++) v[u] = rowp(k[u])[ll];
#pragma unroll
            for (int u = 0; u < 16; u++) {
                ax = fmaf(lo16(v[u]), n[u], ax);
                ay = fmaf(hi16(v[u]), n[u], ay);
            }
        }
        for (; j + 8 <= cnt; j += 8) {
            unsigned k[8];
            float n[8];
            unsigned v[8];
#pragma unroll
            for (int u = 0; u < 8; u++) {
                k[u] = (unsigned)__shfl((int)pl.x, base + j + u);
                n[u] = __builtin_bit_cast(float, (unsigned)__shfl((int)pl.y, base + j + u));
            }
#pragma unroll
            for (int u = 0; u < 8; u++) v[u] = rowp(k[u])[ll];
#pragma unroll
            for (int u = 0; u < 8; u++) {
                ax = fmaf(lo16(v[u]), n[u], ax);
                ay = fmaf(hi16(v[u]), n[u], ay);
            }
        }
        for (; j + 4 <= cnt; j += 4) {
            unsigned k0 = (unsigned)__shfl((int)pl.x, base + j);
            unsigned k1 = (unsigned)__shfl((int)pl.x, base + j + 1);
            unsigned k2 = (unsigned)__shfl((int)pl.x, base + j + 2);
            unsigned k3 = (unsigned)__shfl((int)pl.x, base + j + 3);
            float n0 = __builtin_bit_cast(float, (unsigned)__shfl((int)pl.y, base + j));
            float n1 = __builtin_bit_cast(float, (unsigned)__shfl((int)pl.y, base + j + 1));
            float n2 = __builtin_bit_cast(float, (unsigned)__shfl((int)pl.y, base + j + 2));
            float n3 = __builtin_bit_cast(float, (unsigned)__shfl((int)pl.y, base + j + 3));
            unsigned v0 = rowp(k0)[ll];
            unsigned v1 = rowp(k1)[ll];
            unsigned v2 = rowp(k2)[ll];
            unsigned v3 = rowp(k3)[ll];
            ax = fmaf(lo16(v0), n0, ax); ay = fmaf(hi16(v0), n0, ay);
            ax = fmaf(lo16(v1), n1, ax); ay = fmaf(hi16(v1), n1, ay);
            ax = fmaf(lo16(v2), n2, ax); ay = fmaf(hi16(v2), n2, ay);
            ax = fmaf(lo16(v3), n3, ax); ay = fmaf(hi16(v3), n3, ay);
        }
        for (; j < cnt; j++) {
            unsigned k = (unsigned)__shfl((int)pl.x, base + j);
            float nm = __builtin_bit_cast(float, (unsigned)__shfl((int)pl.y, base + j));
            unsigned v = rowp(k)[ll];
            ax = fmaf(lo16(v), nm, ax);
            ay = fmaf(hi16(v), nm, ay);
        }
    }
    if (OUTMODE == 0) {
        ((unsigned*)out)[(size_t)dst * SUBW + ll] = pack2(fmaxf(ax, 0.f), fmaxf(ay, 0.f));
    } else {
        if (*flagp) {
            ((unsigned*)out)[(size_t)dst * SUBW + ll] = pack2(ax, ay);
        } else {
            float2 v;
            v.x = ax; v.y = ay;
            ((float2*)out)[(size_t)dst * SUBW + ll] = v;
        }
    }
}

// ---------------- fallback path (chunked + atomics, node-major t) ----------------
template <int NOUT, int AMODE>
__global__ __launch_bounds__(256) void gemm_rel(const void* __restrict__ Asrc,
                                                const unsigned short* __restrict__ Wt,
                                                unsigned short* __restrict__ T, int nnodes,
                                                int rbase, const int* __restrict__ flagp) {
    constexpr int LDA = 136;
    __shared__ unsigned short lA[64 * LDA];
    __shared__ unsigned short lB[NOUT * LDA];
    const int tid = threadIdx.x;
    const int node0 = blockIdx.x * 64;
    const int rel = rbase + blockIdx.y;
    const int Gr = gridDim.y;
    const int flag = (AMODE == 0) ? *flagp : 1;

    for (int i = tid; i < 64 * 16; i += 256) {
        int row = i >> 4, seg = i & 15;
        int node = node0 + row;
        uint4 v = make_uint4(0u, 0u, 0u, 0u);
        if (node < nnodes) {
            if (AMODE == 1) {
                const float* p = (const float*)Asrc + (size_t)node * 128 + seg * 8;
                float4 f0 = ((const float4*)p)[0];
                float4 f1 = ((const float4*)p)[1];
                v.x = pack2(fmaxf(f0.x, 0.f), fmaxf(f0.y, 0.f));
                v.y = pack2(fmaxf(f0.z, 0.f), fmaxf(f0.w, 0.f));
                v.z = pack2(fmaxf(f1.x, 0.f), fmaxf(f1.y, 0.f));
                v.w = pack2(fmaxf(f1.z, 0.f), fmaxf(f1.w, 0.f));
            } else if (flag) {
                v = *(const uint4*)((const unsigned short*)Asrc + (size_t)node * 128 + seg * 8);
            } else {
                const float* p = (const float*)Asrc + (size_t)node * 128 + seg * 8;
                float4 f0 = ((const float4*)p)[0];
                float4 f1 = ((const float4*)p)[1];
                v.x = pack2(f0.x, f0.y);
                v.y = pack2(f0.z, f0.w);
                v.z = pack2(f1.x, f1.y);
                v.w = pack2(f1.z, f1.w);
            }
        }
        *(uint4*)(lA + row * LDA + seg * 8) = v;
    }
    for (int i = tid; i < NOUT * 16; i += 256) {
        int o = i >> 4, seg = i & 15;
        *(uint4*)(lB + o * LDA + seg * 8) =
            *(const uint4*)(Wt + ((size_t)rel * NOUT + o) * 128 + seg * 8);
    }
    __syncthreads();

    const int w = tid >> 6, lane = tid & 63;
    const int quad = lane >> 4, mr = lane & 15;
    constexpr int NT = NOUT / 16;
    f32x4 acc[NT];
#pragma unroll
    for (int t = 0; t < NT; t++) acc[t] = 0.f;
    const unsigned short* pa = lA + (w * 16 + mr) * LDA + quad * 8;
    const unsigned short* pb = lB + mr * LDA + quad * 8;
#pragma unroll
    for (int kk = 0; kk < 4; kk++) {
        bf16x8 a = *(const bf16x8*)(pa + kk * 32);
#pragma unroll
        for (int nt = 0; nt < NT; nt++) {
            bf16x8 b = *(const bf16x8*)(pb + nt * 16 * LDA + kk * 32);
            acc[nt] = __builtin_amdgcn_mfma_f32_16x16x32_bf16(a, b, acc[nt], 0, 0, 0);
        }
    }
#pragma unroll
    for (int nt = 0; nt < NT; nt++)
#pragma unroll
        for (int reg = 0; reg < 4; reg++) {
            int node = node0 + w * 16 + quad * 4 + reg;
            if (node < nnodes)
                T[((size_t)node * Gr + blockIdx.y) * NOUT + nt * 16 + mr] = f2bf(acc[nt][reg]);
        }
}

template <int NOUT>
__global__ void scatter_k(const unsigned short* __restrict__ T, int Gr, int rbase,
                          const void* __restrict__ nrm, const int* __restrict__ flagp,
                          const int* __restrict__ src, const int* __restrict__ dst,
                          const int* __restrict__ et, float* __restrict__ accum, int nedges) {
    constexpr int LPE = NOUT / 2;
    const int flag = *flagp;
    const int epb = 256 / LPE;
    const int sub = threadIdx.x % LPE;
    const int slot = threadIdx.x / LPE;
    for (int e = blockIdx.x * epb + slot; e < nedges; e += gridDim.x * epb) {
        int g = et[e] - rbase;
        if (g < 0 || g >= Gr) continue;
        int s = src[e], d = dst[e];
        float nm = flag ? bf2f(((const unsigned short*)nrm)[e]) : ((const float*)nrm)[e];
        unsigned pv = ((const unsigned*)(T + ((size_t)s * Gr + g) * NOUT))[sub];
        float* p = accum + (size_t)d * NOUT + sub * 2;
        unsafeAtomicAdd(p, lo16(pv) * nm);
        unsafeAtomicAdd(p + 1, hi16(pv) * nm);
    }
}

__global__ void write_out(const float* __restrict__ acc, void* __restrict__ dout, int n,
                          const int* __restrict__ flagp) {
    int flag = *flagp;
    int i = blockIdx.x * 256 + threadIdx.x;
    if (i >= n) return;
    float v = acc[i];
    if (flag) ((unsigned short*)dout)[i] = f2bf(v);
    else      ((float*)dout)[i] = v;
}

extern "C" void kernel_launch(void* const* d_in, const int* in_sizes, int n_in,
                              void* d_out, int out_size, void* d_ws, size_t ws_size,
                              hipStream_t stream) {
    const void* feat = d_in[0];
    const void* norm = d_in[1];
    const void* W1 = d_in[2];
    const void* W2 = d_in[3];
    const int* src = (const int*)d_in[4];
    const int* dst = (const int*)d_in[5];
    const int* et  = (const int*)d_in[6];

    const int nnodes = in_sizes[0] / 128;
    const int nedges = in_sizes[1];

    char* ws = (char*)d_ws;
    size_t off = 0;
    auto alloc = [&](size_t bytes) { size_t o = off; off += (bytes + 255) & ~255ULL; return o; };
    size_t off_flag = alloc(4);
    size_t off_w1t  = alloc((size_t)R_NUM * 128 * 128 * 2);
    size_t off_w2t  = alloc((size_t)R_NUM * 64 * 128 * 2);

    int* flagp = (int*)(ws + off_flag);
    unsigned short* w1t = (unsigned short*)(ws + off_w1t);
    unsigned short* w2t = (unsigned short*)(ws + off_w2t);

    const int gx = (nnodes + 63) / 64;
    const int npad = gx * 64;  // padded node count: uniform store counts in gemm_plane
    constexpr int RPB = 4;     // rels per block (occupancy/refetch sweet spot)

    // fast-path layout
    size_t f_off = off;
    auto falloc = [&](size_t bytes) { size_t o = f_off; f_off += (bytes + 255) & ~255ULL; return o; };
    size_t off_offs = falloc((size_t)(nnodes + 1) * 4);
    size_t off_curs = falloc((size_t)nnodes * 4);
    size_t off_cnt  = falloc((size_t)nnodes * 4);
    size_t off_bsum = falloc(1024 * 4);
    size_t off_boff = falloc(1024 * 4);
    size_t off_pay  = falloc((size_t)nedges * 8);
    size_t off_nbf  = falloc((size_t)nnodes * 128 * 2);  // bf16 node buf: feat pass1, h pass2
    size_t off_t    = falloc((size_t)npad * R_NUM * 128 * 2);
    const int nb = (nnodes + 1023) / 1024;
    bool fast = (f_off <= ws_size) && (nb <= 1024);

    const int ntr = R_NUM * 128 * 128 + R_NUM * 128 * 64;

    detect_dtype<<<1, 256, 0, stream>>>((const unsigned short*)feat, flagp);
    transpose_both<<<(ntr + 255) / 256, 256, 0, stream>>>(W1, W2, w1t, w2t, flagp);

    if (fast) {
        int* offs = (int*)(ws + off_offs);
        int* curs = (int*)(ws + off_curs);
        int* cnt  = (int*)(ws + off_cnt);
        int* bsum = (int*)(ws + off_bsum);
        int* boff = (int*)(ws + off_boff);
        uint2* pay = (uint2*)(ws + off_pay);
        unsigned short* nbf = (unsigned short*)(ws + off_nbf);
        unsigned short* t = (unsigned short*)(ws + off_t);

        hipMemsetAsync(cnt, 0, (size_t)nnodes * 4, stream);
        hist_dst<<<(nedges + 255) / 256, 256, 0, stream>>>(dst, cnt, nedges);
        scan_phase1<<<nb, 256, 0, stream>>>(cnt, bsum, nnodes);
        scan_phase2<<<1, 1024, 0, stream>>>(bsum, boff, nb);
        scan_phase3<<<nb, 256, 0, stream>>>(cnt, boff, offs, curs, nnodes);
        fill_payload<<<(nedges + 255) / 256, 256, 0, stream>>>(src, dst, et, norm, flagp,
                                                               curs, pay, nedges);

        const int n8 = nnodes * 16;
        to_bf16<<<(n8 + 255) / 256, 256, 0, stream>>>(feat, nbf, n8, flagp);

        gemm_plane<128, RPB><<<gx * (R_NUM / RPB), 256, 0, stream>>>(nbf, w1t, t, nnodes, npad);
        gather_seg<128, 0><<<(nnodes + 3) / 4, 256, 0, stream>>>(t, offs, pay, nbf, nnodes, npad,
                                                                 flagp);
        gemm_plane<64, RPB><<<gx * (R_NUM / RPB), 256, 0, stream>>>(nbf, w2t, t, nnodes, npad);
        gather_seg<64, 1><<<(nnodes + 7) / 8, 256, 0, stream>>>(t, offs, pay, d_out, nnodes, npad,
                                                                flagp);
        return;
    }

    // fallback: chunked atomic path
    size_t off_hpre = alloc((size_t)nnodes * 128 * 4);
    size_t off_oacc = alloc((size_t)nnodes * 64 * 4);
    size_t t_cap = (ws_size > off) ? (ws_size - off) : 0;
    auto pick_gr = [&](int ncol) {
        int gr = 0;
        for (int g = 16; g >= 1; g >>= 1)
            if ((size_t)nnodes * g * ncol * 2 <= t_cap) { gr = g; break; }
        return gr;
    };
    int Gr1 = pick_gr(128);
    int Gr2 = pick_gr(64);
    if (Gr1 < 1 || Gr2 < 1) {
        hipMemsetAsync(d_out, 0x42, (size_t)out_size * 2, stream);
        return;
    }
    float* hpre = (float*)(ws + off_hpre);
    float* oacc = (float*)(ws + off_oacc);
    unsigned short* t = (unsigned short*)(ws + off);

    hipMemsetAsync(hpre, 0, (size_t)nnodes * 128 * 4, stream);
    hipMemsetAsync(oacc, 0, (size_t)nnodes * 64 * 4, stream);
    for (int rb = 0; rb < R_NUM; rb += Gr1) {
        gemm_rel<128, 0><<<dim3(gx, Gr1), 256, 0, stream>>>(feat, w1t, t, nnodes, rb, flagp);
        scatter_k<128><<<4096, 256, 0, stream>>>(t, Gr1, rb, norm, flagp, src, dst, et, hpre, nedges);
    }
    for (int rb = 0; rb < R_NUM; rb += Gr2) {
        gemm_rel<64, 1><<<dim3(gx, Gr2), 256, 0, stream>>>(hpre, w2t, t, nnodes, rb, flagp);
        scatter_k<64><<<4096, 256, 0, stream>>>(t, Gr2, rb, norm, flagp, src, dst, et, oacc, nedges);
    }
    int nout = nnodes * 64;
    write_out<<<(nout + 255) / 256, 256, 0, stream>>>(oacc, d_out, nout, flagp);
}